// Round 2
// baseline (309.995 us; speedup 1.0000x reference)
//
#include <hip/hip_runtime.h>
#include <cstdint>
#include <cstddef>

// ---------------- problem constants ----------------
#define SCALE  0.08838834764831845f   // 128^-0.5
#define EPS_   1e-8f
#define LN_EPS_ 1e-5f

typedef unsigned short ushort_t;
typedef unsigned int uint_t;

// ---------------- workspace layout (float offsets) ----------------
// total = 2,691,648 floats = 10.8 MB
constexpr int OFF_WKF   = 0;          // 16384  (f_w1@Wk folded)
constexpr int OFF_WVF   = 16384;      // 16384
constexpr int OFF_GFD   = 32768;      // 256    ((f_w1@g_w)/DELTA, [h][2])
constexpr int OFF_CB    = 33024;      // 128    (f_w1@g_b + f_b1)
constexpr int OFF_OQ    = 33152;      // 16384  interleaved (off,qf) per (bs,d)
constexpr int OFF_QB    = 49536;      // 64
constexpr int OFF_SLOTS = 49600;      // 8192
constexpr int OFF_SP    = 57792;      // 128
constexpr int OFF_UP    = 57920;      // 524288 U partials [b][64][8][128]
constexpr int OFF_ZP    = 582208;     // 4096   Z partials [b][64][8]
constexpr int OFF_PP    = 586304;     // 8192   P partials [b][64][8][2]
constexpr int OFF_BKT   = 594496;     // bf16 [b][128][4096] = 1,048,576 float-slots
constexpr int OFF_BV    = 1643072;    // bf16 [b][4096][128] = 1,048,576 float-slots

__device__ __forceinline__ float waveReduceSum(float v) {
#pragma unroll
  for (int m = 1; m < 64; m <<= 1) v += __shfl_xor(v, m, 64);
  return v;
}

__device__ __forceinline__ float bf2f(uint_t u) {
  return __uint_as_float(u << 16);
}
__device__ __forceinline__ ushort_t f2bf(float f) {
  uint_t u = __float_as_uint(f);
  return (ushort_t)((u + 0x7fffu + ((u >> 16) & 1u)) >> 16);
}

// ---------------- kernel: fold weights ----------------
__global__ __launch_bounds__(256) void kFold(
    const float* __restrict__ f_w1, const float* __restrict__ Wk,
    const float* __restrict__ Wv, const float* __restrict__ g_w,
    const float* __restrict__ g_b, const float* __restrict__ f_b1,
    float* __restrict__ ws) {
  int blk = blockIdx.x, tid = threadIdx.x;
  if (blk < 128) {
    int isV = blk >> 6;
    int idx = (blk & 63) * 256 + tid;           // 0..16383
    int h = idx >> 7, e = idx & 127;
    const float* Wm = isV ? Wv : Wk;
    float a = 0.f;
#pragma unroll 4
    for (int d = 0; d < 128; ++d) a = fmaf(f_w1[h * 128 + d], Wm[d * 128 + e], a);
    ws[(isV ? OFF_WVF : OFF_WKF) + idx] = a;
  } else if (blk == 128) {
    int h = tid >> 1, c = tid & 1;
    float a = 0.f;
    for (int d = 0; d < 128; ++d) a = fmaf(f_w1[h * 128 + d], g_w[d * 2 + c], a);
    ws[OFF_GFD + tid] = a * 0.2f;               // /DELTA (DELTA=5)
  } else {
    if (tid < 128) {
      float a = f_b1[tid];
      for (int d = 0; d < 128; ++d) a = fmaf(f_w1[tid * 128 + d], g_b[d], a);
      ws[OFF_CB + tid] = a;
    }
  }
}

// ---------------- kernel: base GEMMs (bf16 out; K transposed) ----------------
// base[row,c] = inputs[row,:] . Wf[c,:] + gy*GFD[c,0] + gx*GFD[c,1] + CB[c]
// isV=0 -> BKT[b][c][n] (bf16, transposed);  isV=1 -> BV[b][n][c] (bf16)
__global__ __launch_bounds__(256) void kBase(const float* __restrict__ inputs,
                                             float* __restrict__ ws) {
  __shared__ float WL[128 * 128];               // 64 KiB, float4-XOR-swizzled
  int tid = threadIdx.x;
  int isV = blockIdx.y;
  const float* Wf = ws + (isV ? OFF_WVF : OFF_WKF);
  // swizzled store: phys float4 idx = row*32 + (c4 ^ (row>>3))
  for (int i = tid; i < 16384; i += 256) {
    int row = i >> 7, col = i & 127;
    WL[(row * 32 + ((col >> 2) ^ (row >> 3))) * 4 + (col & 3)] = Wf[i];
  }
  __syncthreads();
  int rg = tid & 15, cg = tid >> 4;             // 16 row-groups x 16 ch-groups
  int rowbase = blockIdx.x * 128;
  float gf0[8], gf1[8], cbl[8];
#pragma unroll
  for (int j = 0; j < 8; ++j) {
    int c = cg * 8 + j;
    gf0[j] = ws[OFF_GFD + c * 2 + 0];
    gf1[j] = ws[OFF_GFD + c * 2 + 1];
    cbl[j] = ws[OFF_CB + c];
  }
  float acc[8][8];
#pragma unroll
  for (int r = 0; r < 8; ++r)
#pragma unroll
    for (int j = 0; j < 8; ++j) acc[r][j] = 0.f;
  const float* inp = inputs + (size_t)rowbase * 128;
  for (int e4 = 0; e4 < 32; ++e4) {
    float4 iv[8], wv[8];
#pragma unroll
    for (int r = 0; r < 8; ++r)
      iv[r] = *(const float4*)&inp[(r * 16 + rg) * 128 + e4 * 4];
#pragma unroll
    for (int j = 0; j < 8; ++j)
      wv[j] = *(const float4*)&WL[((cg * 8 + j) * 32 + (e4 ^ cg)) * 4];
#pragma unroll
    for (int r = 0; r < 8; ++r)
#pragma unroll
      for (int j = 0; j < 8; ++j) {
        acc[r][j] = fmaf(iv[r].x, wv[j].x, acc[r][j]);
        acc[r][j] = fmaf(iv[r].y, wv[j].y, acc[r][j]);
        acc[r][j] = fmaf(iv[r].z, wv[j].z, acc[r][j]);
        acc[r][j] = fmaf(iv[r].w, wv[j].w, acc[r][j]);
      }
  }
  ushort_t* ktp = (ushort_t*)(ws + OFF_BKT);
  uint_t* bvp = (uint_t*)(ws + OFF_BV);
#pragma unroll
  for (int r = 0; r < 8; ++r) {
    int grow = rowbase + r * 16 + rg;
    int n = grow & 4095, b = grow >> 12;
    float gy = -1.f + (float)(n >> 6) * (2.f / 63.f);
    float gx = -1.f + (float)(n & 63) * (2.f / 63.f);
    float o[8];
#pragma unroll
    for (int j = 0; j < 8; ++j)
      o[j] = acc[r][j] + gy * gf0[j] + gx * gf1[j] + cbl[j];
    if (isV) {
      uint_t p0 = (uint_t)f2bf(o[0]) | ((uint_t)f2bf(o[1]) << 16);
      uint_t p1 = (uint_t)f2bf(o[2]) | ((uint_t)f2bf(o[3]) << 16);
      uint_t p2 = (uint_t)f2bf(o[4]) | ((uint_t)f2bf(o[5]) << 16);
      uint_t p3 = (uint_t)f2bf(o[6]) | ((uint_t)f2bf(o[7]) << 16);
      *(uint4*)&bvp[grow * 64 + cg * 4] = make_uint4(p0, p1, p2, p3);
    } else {
#pragma unroll
      for (int j = 0; j < 8; ++j) {
        int c = cg * 8 + j;
        ktp[(b * 128 + c) * 4096 + n] = f2bf(o[j]);
      }
    }
  }
}

// ---------------- kernel: per-(b,s) q projection + (off,qf) interleaved ----------------
__global__ __launch_bounds__(128) void kQ(
    const float* __restrict__ Wq, const float* __restrict__ f_w2,
    const float* __restrict__ f_b2, const float* __restrict__ ln_g,
    const float* __restrict__ ln_b, float* __restrict__ ws) {
  int bs = blockIdx.x;      // b*8+s
  int d = threadIdx.x;
  int wid = d >> 6, lane = d & 63;
  __shared__ float red[4];
  __shared__ float sn[128], ql[128];
  float x = ws[OFF_SLOTS + bs * 128 + d];
  float s1 = waveReduceSum(x);
  if (lane == 0) red[wid] = s1;
  __syncthreads();
  float mean = (red[0] + red[1]) * (1.f / 128.f);
  float dx = x - mean;
  float s2 = waveReduceSum(dx * dx);
  if (lane == 0) red[2 + wid] = s2;
  __syncthreads();
  float var = (red[2] + red[3]) * (1.f / 128.f);
  float y = dx * rsqrtf(var + LN_EPS_) * ln_g[d] + ln_b[d];
  sn[d] = y;
  __syncthreads();
  float q = 0.f;
#pragma unroll 8
  for (int e = 0; e < 128; ++e) q = fmaf(sn[e], Wq[d * 128 + e], q);
  ql[d] = q;
  __syncthreads();
  float qf = 0.f;
#pragma unroll 8
  for (int e = 0; e < 128; ++e) qf = fmaf(ql[e], f_w2[e * 128 + d], qf);
  float t = ql[d] * f_b2[d];
  float sq = waveReduceSum(t);
  if (lane == 0) red[wid] = sq;
  __syncthreads();
  if (d == 0) ws[OFF_QB + bs] = (red[0] + red[1]) * SCALE;
  float sp0 = ws[OFF_SP + bs * 2 + 0], sp1 = ws[OFF_SP + bs * 2 + 1];
  float offd = -(sp0 * ws[OFF_GFD + d * 2 + 0] + sp1 * ws[OFF_GFD + d * 2 + 1]);
  ws[OFF_OQ + (bs * 128 + d) * 2 + 0] = offd;
  ws[OFF_OQ + (bs * 128 + d) * 2 + 1] = qf * SCALE;
}

// ---------------- kernel: fused attention, 1 wave / 64 pixels ----------------
// grid 512 = 8 b * 64 chunks, block 64
__global__ __launch_bounds__(64) void kAttn(float* __restrict__ ws) {
  __shared__ float2 OQl[8][128];   // 8 KiB
  __shared__ float al[64][9];      // attn weights, padded
  int b = blockIdx.x >> 6, chunk = blockIdx.x & 63;
  int lane = threadIdx.x;
  int sb = b * 8;
  // stage OQ for this b's 8 slots
  for (int f = lane; f < 1024; f += 64) {
    int s = f >> 7, d = f & 127;
    OQl[s][d] = *(const float2*)&ws[OFF_OQ + ((sb + s) * 128 + d) * 2];
  }
  float qbl[8];
#pragma unroll
  for (int s = 0; s < 8; ++s) qbl[s] = ws[OFF_QB + sb + s];
  __syncthreads();

  // ---- phase 1: dots, pixel-per-lane against transposed bf16 K ----
  int n = chunk * 64 + lane;
  const ushort_t* kp = (const ushort_t*)(ws + OFF_BKT) + (size_t)b * 524288 + n;
  float t[8];
#pragma unroll
  for (int s = 0; s < 8; ++s) t[s] = 0.f;
#pragma unroll 4
  for (int dd = 0; dd < 128; ++dd) {
    float kv = bf2f((uint_t)kp[dd * 4096]);
#pragma unroll
    for (int s = 0; s < 8; ++s) {
      float2 oq = OQl[s][dd];
      t[s] = fmaf(fmaxf(kv + oq.x, 0.f), oq.y, t[s]);
    }
  }
  float mx = t[0] + qbl[0];
#pragma unroll
  for (int s = 0; s < 8; ++s) { t[s] += qbl[s]; mx = fmaxf(mx, t[s]); }
  float a[8], den = 0.f;
#pragma unroll
  for (int s = 0; s < 8; ++s) { a[s] = __expf(t[s] - mx); den += a[s]; }
  float inv = 1.0f / den;
  float gy = -1.f + (float)(n >> 6) * (2.f / 63.f);
  float gx = -1.f + (float)(n & 63) * (2.f / 63.f);
#pragma unroll
  for (int s = 0; s < 8; ++s) {
    a[s] = fmaf(a[s], inv, EPS_);
    al[lane][s] = a[s];
  }
  // Z / P partial sums (wave reduce), lane 0 writes
  float zz[1];
  (void)zz;
#pragma unroll
  for (int s = 0; s < 8; ++s) {
    float z = waveReduceSum(a[s]);
    float p0 = waveReduceSum(a[s] * gy);
    float p1 = waveReduceSum(a[s] * gx);
    if (lane == 0) {
      ws[OFF_ZP + (b * 64 + chunk) * 8 + s] = z;
      ws[OFF_PP + ((b * 64 + chunk) * 8 + s) * 2 + 0] = p0;
      ws[OFF_PP + ((b * 64 + chunk) * 8 + s) * 2 + 1] = p1;
    }
  }
  __syncthreads();

  // ---- phase 2: weighted V accumulation, channel-pair-per-lane ----
  int c0 = 2 * lane;
  float offv0[8], offv1[8];
#pragma unroll
  for (int s = 0; s < 8; ++s) {
    offv0[s] = OQl[s][c0].x;
    offv1[s] = OQl[s][c0 + 1].x;
  }
  float Ua0[8], Ua1[8];
#pragma unroll
  for (int s = 0; s < 8; ++s) { Ua0[s] = 0.f; Ua1[s] = 0.f; }
  const ushort_t* vp = (const ushort_t*)(ws + OFF_BV) +
                       ((size_t)(b * 4096 + chunk * 64)) * 128 + c0;
#pragma unroll 2
  for (int i = 0; i < 64; ++i) {
    uint_t vraw = *(const uint_t*)(vp + (size_t)i * 128);
    float v0 = bf2f(vraw & 0xffffu);
    float v1 = bf2f(vraw >> 16);
#pragma unroll
    for (int s = 0; s < 8; ++s) {
      float as = al[i][s];
      Ua0[s] = fmaf(as, fmaxf(v0 + offv0[s], 0.f), Ua0[s]);
      Ua1[s] = fmaf(as, fmaxf(v1 + offv1[s], 0.f), Ua1[s]);
    }
  }
#pragma unroll
  for (int s = 0; s < 8; ++s)
    *(float2*)&ws[OFF_UP + ((b * 64 + chunk) * 8 + s) * 128 + c0] =
        make_float2(Ua0[s], Ua1[s]);
}

// ---------------- kernel: partial-sum + GRU + post-MLP ----------------
__global__ __launch_bounds__(128) void kC(
    const float* __restrict__ f_w2, const float* __restrict__ f_b2,
    const float* __restrict__ wih, const float* __restrict__ whh,
    const float* __restrict__ bih, const float* __restrict__ bhh,
    const float* __restrict__ mw1, const float* __restrict__ mb1,
    const float* __restrict__ mw2, const float* __restrict__ mb2,
    const float* __restrict__ lng, const float* __restrict__ lnb,
    float* __restrict__ ws) {
  int bs = blockIdx.x, d = threadIdx.x;
  int b = bs >> 3, s = bs & 7;
  int wid = d >> 6, lane = d & 63;
  __shared__ float red[4];
  __shared__ float ul[128], xl[128], hl[128], yl[128], hml[128];
  // sum partials
  float u = 0.f;
  const float* up = ws + OFF_UP + ((size_t)(b * 64) * 8 + s) * 128 + d;
#pragma unroll 8
  for (int ch = 0; ch < 64; ++ch) u += up[ch * 1024];
  float Z = 0.f, P0 = 0.f, P1 = 0.f;
  const float* zp = ws + OFF_ZP + b * 512 + s;
  const float* pp = ws + OFF_PP + b * 1024 + s * 2;
#pragma unroll 8
  for (int ch = 0; ch < 64; ++ch) {
    Z += zp[ch * 8];
    P0 += pp[ch * 16];
    P1 += pp[ch * 16 + 1];
  }
  float invZ = 1.0f / Z;
  ul[d] = u * invZ;
  if (d == 0) {
    ws[OFF_SP + bs * 2 + 0] = P0 * invZ;
    ws[OFF_SP + bs * 2 + 1] = P1 * invZ;
  }
  float hprev = ws[OFF_SLOTS + bs * 128 + d];
  hl[d] = hprev;
  __syncthreads();
  float upd = f_b2[d];
#pragma unroll 8
  for (int e = 0; e < 128; ++e) upd = fmaf(ul[e], f_w2[d * 128 + e], upd);
  xl[d] = upd;
  __syncthreads();
  float ir = bih[d], iz = bih[128 + d], inn = bih[256 + d];
  float hr = bhh[d], hz = bhh[128 + d], hn = bhh[256 + d];
#pragma unroll 4
  for (int e = 0; e < 128; ++e) {
    float xe = xl[e], he = hl[e];
    ir = fmaf(xe, wih[d * 128 + e], ir);
    iz = fmaf(xe, wih[(128 + d) * 128 + e], iz);
    inn = fmaf(xe, wih[(256 + d) * 128 + e], inn);
    hr = fmaf(he, whh[d * 128 + e], hr);
    hz = fmaf(he, whh[(128 + d) * 128 + e], hz);
    hn = fmaf(he, whh[(256 + d) * 128 + e], hn);
  }
  float r = 1.f / (1.f + __expf(-(ir + hr)));
  float z = 1.f / (1.f + __expf(-(iz + hz)));
  float nn = tanhf(inn + r * hn);
  float hnew = (1.f - z) * nn + z * hprev;
  float s1 = waveReduceSum(hnew);
  if (lane == 0) red[wid] = s1;
  __syncthreads();
  float mean = (red[0] + red[1]) * (1.f / 128.f);
  float dx = hnew - mean;
  float s2 = waveReduceSum(dx * dx);
  if (lane == 0) red[2 + wid] = s2;
  __syncthreads();
  float var = (red[2] + red[3]) * (1.f / 128.f);
  float y = dx * rsqrtf(var + LN_EPS_) * lng[d] + lnb[d];
  yl[d] = y;
  __syncthreads();
  float hm = mb1[d];
#pragma unroll 8
  for (int e = 0; e < 128; ++e) hm = fmaf(yl[e], mw1[d * 128 + e], hm);
  hml[d] = fmaxf(hm, 0.f);
  __syncthreads();
  float o = hnew + mb2[d];
#pragma unroll 8
  for (int e = 0; e < 128; ++e) o = fmaf(hml[e], mw2[d * 128 + e], o);
  ws[OFF_SLOTS + bs * 128 + d] = o;
}

// ---------------- kernel: write outputs ----------------
__global__ __launch_bounds__(256) void kOut(const float* __restrict__ ws,
                                            const float* __restrict__ S_r,
                                            const float* __restrict__ S_s,
                                            float* __restrict__ out) {
  int i = blockIdx.x * 256 + threadIdx.x;
  if (i < 8192) out[i] = ws[OFF_SLOTS + i];
  else if (i < 8320) out[i] = ws[OFF_SP + i - 8192];
  else if (i < 8576) out[i] = S_r[i - 8320];
  else if (i < 8704) out[i] = S_s[i - 8576];
}

extern "C" void kernel_launch(void* const* d_in, const int* in_sizes, int n_in,
                              void* d_out, int out_size, void* d_ws, size_t ws_size,
                              hipStream_t stream) {
  const float* inputs     = (const float*)d_in[0];
  const float* slots_init = (const float*)d_in[1];
  const float* S_p0       = (const float*)d_in[2];
  const float* S_s        = (const float*)d_in[3];
  const float* S_r        = (const float*)d_in[4];
  const float* Wq   = (const float*)d_in[5];
  const float* Wk   = (const float*)d_in[6];
  const float* Wv   = (const float*)d_in[7];
  const float* g_w  = (const float*)d_in[8];
  const float* g_b  = (const float*)d_in[9];
  const float* f_w1 = (const float*)d_in[10];
  const float* f_b1 = (const float*)d_in[11];
  const float* f_w2 = (const float*)d_in[12];
  const float* f_b2 = (const float*)d_in[13];
  const float* gwih = (const float*)d_in[14];
  const float* gwhh = (const float*)d_in[15];
  const float* gbih = (const float*)d_in[16];
  const float* gbhh = (const float*)d_in[17];
  const float* mw1  = (const float*)d_in[18];
  const float* mb1  = (const float*)d_in[19];
  const float* mw2  = (const float*)d_in[20];
  const float* mb2  = (const float*)d_in[21];
  const float* lnsg = (const float*)d_in[22];
  const float* lnsb = (const float*)d_in[23];
  const float* lnpg = (const float*)d_in[24];
  const float* lnpb = (const float*)d_in[25];
  float* ws  = (float*)d_ws;
  float* out = (float*)d_out;

  hipMemcpyAsync(ws + OFF_SLOTS, slots_init, 8192 * sizeof(float),
                 hipMemcpyDeviceToDevice, stream);
  hipMemcpyAsync(ws + OFF_SP, S_p0, 128 * sizeof(float),
                 hipMemcpyDeviceToDevice, stream);
  kFold<<<130, 256, 0, stream>>>(f_w1, Wk, Wv, g_w, g_b, f_b1, ws);
  kBase<<<dim3(256, 2), 256, 0, stream>>>(inputs, ws);
  for (int it = 0; it < 3; ++it) {
    kQ<<<64, 128, 0, stream>>>(Wq, f_w2, f_b2, lnsg, lnsb, ws);
    kAttn<<<512, 64, 0, stream>>>(ws);
    kC<<<64, 128, 0, stream>>>(f_w2, f_b2, gwih, gwhh, gbih, gbhh,
                               mw1, mb1, mw2, mb2, lnpg, lnpb, ws);
  }
  kOut<<<35, 256, 0, stream>>>(ws, S_r, S_s, out);
}

// Round 3
// 231.279 us; speedup vs baseline: 1.3404x; 1.3404x over previous
//
#include <hip/hip_runtime.h>
#include <cstdint>
#include <cstddef>

#define SCALE  0.08838834764831845f   // 128^-0.5
#define EPS_   1e-8f
#define LN_EPS_ 1e-5f

typedef unsigned short ushort_t;
typedef unsigned int uint_t;
typedef __attribute__((ext_vector_type(8))) short short8;
typedef __attribute__((ext_vector_type(4))) float f32x4;

// ---------------- workspace layout (float offsets), ~19.1 MB ----------------
constexpr int OFF_GFD   = 0;        // 256   (f_w1@g_w)/DELTA  [h][2]
constexpr int OFF_CB    = 256;      // 128   f_w1@g_b + f_b1
constexpr int OFF_QB    = 384;      // 64
constexpr int OFF_SP    = 448;      // 128
constexpr int OFF_OQ    = 576;      // 16384 interleaved (off, qf*scale)
constexpr int OFF_SLOTS = 16960;    // 8192
constexpr int OFF_ZP    = 25152;    // 4096  [b][64][8]
constexpr int OFF_PP    = 29248;    // 8192  [b][64][8][2]
constexpr int OFF_UP    = 37440;    // 524288 [b][64][8][128]
constexpr int OFF_WKB   = 561728;   // bf16 [128][128] = 8192 float-slots
constexpr int OFF_WVB   = 569920;   // 8192
constexpr int OFF_AB    = 578112;   // bf16 inputs [32768][128] = 2097152 slots
constexpr int OFF_BKT   = 2675264;  // bf16 [b][128][4096] = 1048576 slots
constexpr int OFF_BV    = 3723840;  // bf16 [b][4096][128] = 1048576 slots

__device__ __forceinline__ float waveReduceSum(float v) {
#pragma unroll
  for (int m = 1; m < 64; m <<= 1) v += __shfl_xor(v, m, 64);
  return v;
}
__device__ __forceinline__ float bf2f(uint_t u) { return __uint_as_float(u << 16); }
__device__ __forceinline__ ushort_t f2bf(float f) {
  uint_t u = __float_as_uint(f);
  return (ushort_t)((u + 0x7fffu + ((u >> 16) & 1u)) >> 16);
}

// ---------------- cast inputs f32 -> bf16 ----------------
__global__ __launch_bounds__(256) void kCast(const float* __restrict__ in,
                                             float* __restrict__ ws) {
  int idx = blockIdx.x * 256 + threadIdx.x;      // 0..524287, 8 elems each
  const float4* src = (const float4*)(in + (size_t)idx * 8);
  float4 a = src[0], b = src[1];
  uint_t p0 = (uint_t)f2bf(a.x) | ((uint_t)f2bf(a.y) << 16);
  uint_t p1 = (uint_t)f2bf(a.z) | ((uint_t)f2bf(a.w) << 16);
  uint_t p2 = (uint_t)f2bf(b.x) | ((uint_t)f2bf(b.y) << 16);
  uint_t p3 = (uint_t)f2bf(b.z) | ((uint_t)f2bf(b.w) << 16);
  ((uint4*)((ushort_t*)(ws + OFF_AB)))[idx] = make_uint4(p0, p1, p2, p3);
}

// ---------------- fold weights: WF = f_w1@W (bf16), GFD, CB ----------------
__global__ __launch_bounds__(256) void kFold(
    const float* __restrict__ f_w1, const float* __restrict__ Wk,
    const float* __restrict__ Wv, const float* __restrict__ g_w,
    const float* __restrict__ g_b, const float* __restrict__ f_b1,
    float* __restrict__ ws) {
  int blk = blockIdx.x, tid = threadIdx.x;
  if (blk < 128) {
    int isV = blk >> 6;
    int idx = (blk & 63) * 256 + tid;           // 0..16383  (h*128+e)
    int h = idx >> 7, e = idx & 127;
    const float* Wm = isV ? Wv : Wk;
    float a = 0.f;
#pragma unroll 4
    for (int d = 0; d < 128; ++d) a = fmaf(f_w1[h * 128 + d], Wm[d * 128 + e], a);
    ((ushort_t*)(ws + (isV ? OFF_WVB : OFF_WKB)))[idx] = f2bf(a);
  } else if (blk == 128) {
    int h = tid >> 1, c = tid & 1;
    float a = 0.f;
    for (int d = 0; d < 128; ++d) a = fmaf(f_w1[h * 128 + d], g_w[d * 2 + c], a);
    ws[OFF_GFD + tid] = a * 0.2f;               // /DELTA (DELTA=5)
  } else {
    if (tid < 128) {
      float a = f_b1[tid];
      for (int d = 0; d < 128; ++d) a = fmaf(f_w1[tid * 128 + d], g_b[d], a);
      ws[OFF_CB + tid] = a;
    }
  }
}

// ---------------- MFMA base GEMMs ----------------
// block: 256 thr (4 waves), 128 rows; waves own 32 rows (2 row-tiles of 16).
// mat 0 -> BKT[b][c][n] (transposed), mat 1 -> BV[b][n][c]. Both bf16.
__global__ __launch_bounds__(256) void kBase(float* __restrict__ ws) {
  __shared__ __align__(16) char smem[32768 + 17408];
  char* wsm = smem;                 // 32 KB swizzled W tile
  char* ep  = smem + 32768;         // epilogue transpose buffer
  const ushort_t* ab = (const ushort_t*)(ws + OFF_AB);
  int tid = threadIdx.x, w = tid >> 6, l = tid & 63;
  int lr = l & 15, lg = l >> 4;
  int blk = blockIdx.x;
  int rowblk = blk * 128;
  int b = blk >> 5;
  int nb_in_b = (blk & 31) * 128;

  // A fragments: rows = rowblk + w*32 + rt*16 + lr, k = ks*32 + lg*8
  short8 afrag[2][4];
#pragma unroll
  for (int rt = 0; rt < 2; ++rt)
#pragma unroll
    for (int ks = 0; ks < 4; ++ks) {
      size_t row = (size_t)rowblk + w * 32 + rt * 16 + lr;
      afrag[rt][ks] = *(const short8*)(ab + row * 128 + ks * 32 + lg * 8);
    }
  // affine coefficients per col
  float gf0a[8], gf1a[8], cba[8];
#pragma unroll
  for (int ct = 0; ct < 8; ++ct) {
    int c = ct * 16 + lr;
    gf0a[ct] = ws[OFF_GFD + c * 2 + 0];
    gf1a[ct] = ws[OFF_GFD + c * 2 + 1];
    cba[ct]  = ws[OFF_CB + c];
  }
  ushort_t* outK = (ushort_t*)(ws + OFF_BKT);
  ushort_t* outV = (ushort_t*)(ws + OFF_BV);

  for (int mat = 0; mat < 2; ++mat) {
    const uint4* wsrc = (const uint4*)(ws + (mat ? OFF_WVB : OFF_WKB));
    __syncthreads();
    for (int f = tid; f < 2048; f += 256) {      // stage W swizzled
      int c = f >> 4, kg = f & 15;
      int byte = c * 256 + kg * 16;
      *(uint4*)(wsm + (byte ^ ((c & 7) << 4))) = wsrc[f];
    }
    __syncthreads();
    f32x4 acc[2][8];
#pragma unroll
    for (int rt = 0; rt < 2; ++rt)
#pragma unroll
      for (int ct = 0; ct < 8; ++ct) acc[rt][ct] = (f32x4){0.f, 0.f, 0.f, 0.f};
#pragma unroll 2
    for (int ct = 0; ct < 8; ++ct) {
      short8 bfr[4];
#pragma unroll
      for (int ks = 0; ks < 4; ++ks) {
        int c = ct * 16 + lr;
        int byte = c * 256 + ks * 64 + lg * 16;
        bfr[ks] = *(const short8*)(wsm + (byte ^ ((c & 7) << 4)));
      }
#pragma unroll
      for (int ks = 0; ks < 4; ++ks) {
        acc[0][ct] = __builtin_amdgcn_mfma_f32_16x16x32_bf16(afrag[0][ks], bfr[ks], acc[0][ct], 0, 0, 0);
        acc[1][ct] = __builtin_amdgcn_mfma_f32_16x16x32_bf16(afrag[1][ks], bfr[ks], acc[1][ct], 0, 0, 0);
      }
    }
    // epilogue: two 64-row halves through LDS transpose buffer
    for (int h = 0; h < 2; ++h) {
      __syncthreads();
      if ((w >> 1) == h) {
        int nl0 = (w & 1) * 32 + lg * 4;
#pragma unroll
        for (int rt = 0; rt < 2; ++rt)
#pragma unroll
          for (int ct = 0; ct < 8; ++ct) {
            int c = ct * 16 + lr;
            ushort_t pk[4];
#pragma unroll
            for (int r = 0; r < 4; ++r) {
              int n = nb_in_b + h * 64 + nl0 + rt * 16 + r;
              float gy = -1.f + (float)(n >> 6) * (2.f / 63.f);
              float gx = -1.f + (float)(n & 63) * (2.f / 63.f);
              float o = acc[rt][ct][r] + gy * gf0a[ct] + gx * gf1a[ct] + cba[ct];
              pk[r] = f2bf(o);
            }
            if (mat == 0) {   // epK: [c][64 n] bf16, swizzled rows of 128B
              int byte = (c * 128 + (nl0 + rt * 16) * 2) ^ ((c & 7) << 4);
              *(uint2*)(ep + byte) = make_uint2(
                  (uint_t)pk[0] | ((uint_t)pk[1] << 16),
                  (uint_t)pk[2] | ((uint_t)pk[3] << 16));
            } else {          // epV: [64 n][136 c-pad] bf16 rows of 272B
              int rb = nl0 + rt * 16;
#pragma unroll
              for (int r = 0; r < 4; ++r)
                *(ushort_t*)(ep + (rb + r) * 272 + c * 2) = pk[r];
            }
          }
      }
      __syncthreads();
      if (mat == 0) {         // coalesced BKT store: thread -> (c, 32-n chunk)
        int c = tid >> 1, q = tid & 1;
        size_t gbase = ((size_t)(b * 128 + c)) * 4096 + nb_in_b + h * 64 + q * 32;
#pragma unroll
        for (int i = 0; i < 4; ++i) {
          uint4 v = *(const uint4*)(ep + ((c * 128 + q * 64 + i * 16) ^ ((c & 7) << 4)));
          *(uint4*)(outK + gbase + i * 8) = v;
        }
      } else {                // coalesced BV store: thread -> (n, 32-c chunk)
        int nl = tid >> 2, q = tid & 3;
        size_t row = (size_t)rowblk + h * 64 + nl;
#pragma unroll
        for (int i = 0; i < 4; ++i) {
          uint4 v = *(const uint4*)(ep + nl * 272 + q * 64 + i * 16);
          *(uint4*)(outV + row * 128 + q * 32 + i * 8) = v;
        }
      }
    }
  }
}

// ---------------- initial q projection (iteration 0) ----------------
__global__ __launch_bounds__(128) void kQ(
    const float* __restrict__ Wq, const float* __restrict__ f_w2,
    const float* __restrict__ f_b2, const float* __restrict__ ln_g,
    const float* __restrict__ ln_b, float* __restrict__ ws) {
  int bs = blockIdx.x;
  int d = threadIdx.x;
  int wid = d >> 6, lane = d & 63;
  __shared__ float red[4];
  __shared__ float sn[128], ql[128];
  float x = ws[OFF_SLOTS + bs * 128 + d];
  float s1 = waveReduceSum(x);
  if (lane == 0) red[wid] = s1;
  __syncthreads();
  float mean = (red[0] + red[1]) * (1.f / 128.f);
  float dx = x - mean;
  float s2 = waveReduceSum(dx * dx);
  if (lane == 0) red[2 + wid] = s2;
  __syncthreads();
  float var = (red[2] + red[3]) * (1.f / 128.f);
  float y = dx * rsqrtf(var + LN_EPS_) * ln_g[d] + ln_b[d];
  sn[d] = y;
  __syncthreads();
  float q = 0.f;
#pragma unroll 8
  for (int e = 0; e < 128; ++e) q = fmaf(sn[e], Wq[d * 128 + e], q);
  ql[d] = q;
  __syncthreads();
  float qf = 0.f;
#pragma unroll 8
  for (int e = 0; e < 128; ++e) qf = fmaf(ql[e], f_w2[e * 128 + d], qf);
  float t = ql[d] * f_b2[d];
  float sq = waveReduceSum(t);
  if (lane == 0) red[wid] = sq;
  __syncthreads();
  if (d == 0) ws[OFF_QB + bs] = (red[0] + red[1]) * SCALE;
  float sp0 = ws[OFF_SP + bs * 2 + 0], sp1 = ws[OFF_SP + bs * 2 + 1];
  float offd = -(sp0 * ws[OFF_GFD + d * 2 + 0] + sp1 * ws[OFF_GFD + d * 2 + 1]);
  ws[OFF_OQ + (bs * 128 + d) * 2 + 0] = offd;
  ws[OFF_OQ + (bs * 128 + d) * 2 + 1] = qf * SCALE;
}

// ---------------- fused attention: 4 waves, d-split / i-split ----------------
__global__ __launch_bounds__(256) void kAttn(float* __restrict__ ws) {
  __shared__ float2 OQl[8][128];     // 8 KB
  __shared__ float tp[64][37];       // phase-1 partials (pad 37: stride 5 mod 32)
  __shared__ float al[64][13];       // attn weights (pad 13)
  __shared__ float Ush[4][8][132];   // phase-2 partials
  int b = blockIdx.x >> 6, chunk = blockIdx.x & 63;
  int tid = threadIdx.x, w = tid >> 6, lane = tid & 63;
  int sb = b * 8;
  for (int f = tid; f < 1024; f += 256) {
    int s = f >> 7, d = f & 127;
    OQl[s][d] = *(const float2*)&ws[OFF_OQ + ((sb + s) * 128 + d) * 2];
  }
  float qbl[8];
#pragma unroll
  for (int s = 0; s < 8; ++s) qbl[s] = ws[OFF_QB + sb + s];
  __syncthreads();

  // phase 1: pixel-per-lane dots over this wave's d-quarter
  int n = chunk * 64 + lane;
  const ushort_t* kp = (const ushort_t*)(ws + OFF_BKT) +
                       (size_t)b * 524288 + (size_t)w * 32 * 4096 + n;
  float t[8];
#pragma unroll
  for (int s = 0; s < 8; ++s) t[s] = 0.f;
#pragma unroll 4
  for (int dd = 0; dd < 32; ++dd) {
    int d = w * 32 + dd;
    float kv = bf2f((uint_t)kp[(size_t)dd * 4096]);
#pragma unroll
    for (int s = 0; s < 8; ++s) {
      float2 oq = OQl[s][d];
      t[s] = fmaf(fmaxf(kv + oq.x, 0.f), oq.y, t[s]);
    }
  }
#pragma unroll
  for (int s = 0; s < 8; ++s) tp[lane][s * 4 + w] = t[s];
  __syncthreads();
  float a[8], den = 0.f;
#pragma unroll
  for (int s = 0; s < 8; ++s)
    t[s] = tp[lane][s * 4 + 0] + tp[lane][s * 4 + 1] +
           tp[lane][s * 4 + 2] + tp[lane][s * 4 + 3] + qbl[s];
  float mx = t[0];
#pragma unroll
  for (int s = 1; s < 8; ++s) mx = fmaxf(mx, t[s]);
#pragma unroll
  for (int s = 0; s < 8; ++s) { a[s] = __expf(t[s] - mx); den += a[s]; }
  float inv = 1.0f / den;
#pragma unroll
  for (int s = 0; s < 8; ++s) a[s] = fmaf(a[s], inv, EPS_);
  if (w == 0) {
    float gy = -1.f + (float)(n >> 6) * (2.f / 63.f);
    float gx = -1.f + (float)(n & 63) * (2.f / 63.f);
#pragma unroll
    for (int s = 0; s < 8; ++s) al[lane][s] = a[s];
#pragma unroll
    for (int s = 0; s < 8; ++s) {
      float z = waveReduceSum(a[s]);
      float p0 = waveReduceSum(a[s] * gy);
      float p1 = waveReduceSum(a[s] * gx);
      if (lane == 0) {
        ws[OFF_ZP + (b * 64 + chunk) * 8 + s] = z;
        ws[OFF_PP + ((b * 64 + chunk) * 8 + s) * 2 + 0] = p0;
        ws[OFF_PP + ((b * 64 + chunk) * 8 + s) * 2 + 1] = p1;
      }
    }
  }
  __syncthreads();

  // phase 2: channel-pair-per-lane over this wave's 16 pixels
  int c0 = 2 * lane;
  float offv0[8], offv1[8];
#pragma unroll
  for (int s = 0; s < 8; ++s) {
    offv0[s] = OQl[s][c0].x;
    offv1[s] = OQl[s][c0 + 1].x;
  }
  float Ua0[8], Ua1[8];
#pragma unroll
  for (int s = 0; s < 8; ++s) { Ua0[s] = 0.f; Ua1[s] = 0.f; }
  const ushort_t* vp = (const ushort_t*)(ws + OFF_BV) +
                       ((size_t)(b * 4096 + chunk * 64 + w * 16)) * 128 + c0;
#pragma unroll 4
  for (int i = 0; i < 16; ++i) {
    uint_t vraw = *(const uint_t*)(vp + (size_t)i * 128);
    float v0 = bf2f(vraw & 0xffffu);
    float v1 = bf2f(vraw >> 16);
    int ii = w * 16 + i;
#pragma unroll
    for (int s = 0; s < 8; ++s) {
      float as = al[ii][s];
      Ua0[s] = fmaf(as, fmaxf(v0 + offv0[s], 0.f), Ua0[s]);
      Ua1[s] = fmaf(as, fmaxf(v1 + offv1[s], 0.f), Ua1[s]);
    }
  }
#pragma unroll
  for (int s = 0; s < 8; ++s)
    *(float2*)&Ush[w][s][c0] = make_float2(Ua0[s], Ua1[s]);
  __syncthreads();
  for (int f = tid; f < 1024; f += 256) {
    int s = f >> 7, c = f & 127;
    float v = Ush[0][s][c] + Ush[1][s][c] + Ush[2][s][c] + Ush[3][s][c];
    ws[OFF_UP + ((size_t)(b * 64 + chunk) * 8 + s) * 128 + c] = v;
  }
}

// ---------------- fused: finalize + GRU + post-MLP + next-iter q ----------------
__global__ __launch_bounds__(128) void kCQ(
    const float* __restrict__ Wq, const float* __restrict__ f_w2,
    const float* __restrict__ f_b2, const float* __restrict__ wih,
    const float* __restrict__ whh, const float* __restrict__ bih,
    const float* __restrict__ bhh, const float* __restrict__ mw1,
    const float* __restrict__ mb1, const float* __restrict__ mw2,
    const float* __restrict__ mb2, const float* __restrict__ lnpg,
    const float* __restrict__ lnpb, const float* __restrict__ lnsg,
    const float* __restrict__ lnsb, float* __restrict__ ws) {
  int bs = blockIdx.x, d = threadIdx.x;
  int b = bs >> 3, s = bs & 7;
  int wid = d >> 6, lane = d & 63;
  __shared__ float red[4];
  __shared__ float spl[2];
  __shared__ float ul[128], xl[128], hl[128], yl[128], hml[128];
  float u = 0.f;
  const float* up = ws + OFF_UP + ((size_t)(b * 64) * 8 + s) * 128 + d;
#pragma unroll 8
  for (int ch = 0; ch < 64; ++ch) u += up[(size_t)ch * 1024];
  float Z = 0.f, P0 = 0.f, P1 = 0.f;
  const float* zp = ws + OFF_ZP + b * 512 + s;
  const float* pp = ws + OFF_PP + b * 1024 + s * 2;
#pragma unroll 8
  for (int ch = 0; ch < 64; ++ch) {
    Z += zp[ch * 8];
    P0 += pp[ch * 16];
    P1 += pp[ch * 16 + 1];
  }
  float invZ = 1.0f / Z;
  ul[d] = u * invZ;
  if (d == 0) {
    float sp0 = P0 * invZ, sp1 = P1 * invZ;
    ws[OFF_SP + bs * 2 + 0] = sp0;
    ws[OFF_SP + bs * 2 + 1] = sp1;
    spl[0] = sp0; spl[1] = sp1;
  }
  float hprev = ws[OFF_SLOTS + bs * 128 + d];
  hl[d] = hprev;
  __syncthreads();
  float upd = f_b2[d];
#pragma unroll 8
  for (int e = 0; e < 128; ++e) upd = fmaf(ul[e], f_w2[d * 128 + e], upd);
  xl[d] = upd;
  __syncthreads();
  float ir = bih[d], iz = bih[128 + d], inn = bih[256 + d];
  float hr = bhh[d], hz = bhh[128 + d], hn = bhh[256 + d];
#pragma unroll 4
  for (int e = 0; e < 128; ++e) {
    float xe = xl[e], he = hl[e];
    ir = fmaf(xe, wih[d * 128 + e], ir);
    iz = fmaf(xe, wih[(128 + d) * 128 + e], iz);
    inn = fmaf(xe, wih[(256 + d) * 128 + e], inn);
    hr = fmaf(he, whh[d * 128 + e], hr);
    hz = fmaf(he, whh[(128 + d) * 128 + e], hz);
    hn = fmaf(he, whh[(256 + d) * 128 + e], hn);
  }
  float r = 1.f / (1.f + __expf(-(ir + hr)));
  float z = 1.f / (1.f + __expf(-(iz + hz)));
  float nn = tanhf(inn + r * hn);
  float hnew = (1.f - z) * nn + z * hprev;
  float s1 = waveReduceSum(hnew);
  if (lane == 0) red[wid] = s1;
  __syncthreads();
  float mean = (red[0] + red[1]) * (1.f / 128.f);
  float dx = hnew - mean;
  float s2 = waveReduceSum(dx * dx);
  if (lane == 0) red[2 + wid] = s2;
  __syncthreads();
  float var = (red[2] + red[3]) * (1.f / 128.f);
  float y = dx * rsqrtf(var + LN_EPS_) * lnpg[d] + lnpb[d];
  yl[d] = y;
  __syncthreads();
  float hm = mb1[d];
#pragma unroll 8
  for (int e = 0; e < 128; ++e) hm = fmaf(yl[e], mw1[d * 128 + e], hm);
  hml[d] = fmaxf(hm, 0.f);
  __syncthreads();
  float o = hnew + mb2[d];
#pragma unroll 8
  for (int e = 0; e < 128; ++e) o = fmaf(hml[e], mw2[d * 128 + e], o);
  ws[OFF_SLOTS + bs * 128 + d] = o;
  // ---- next-iteration q generation (LN_s -> Wq -> f_w2 folding) ----
  float q1 = waveReduceSum(o);
  if (lane == 0) red[wid] = q1;
  __syncthreads();
  float mean2 = (red[0] + red[1]) * (1.f / 128.f);
  float dx2 = o - mean2;
  float q2 = waveReduceSum(dx2 * dx2);
  if (lane == 0) red[2 + wid] = q2;
  __syncthreads();
  float var2 = (red[2] + red[3]) * (1.f / 128.f);
  float y2 = dx2 * rsqrtf(var2 + LN_EPS_) * lnsg[d] + lnsb[d];
  yl[d] = y2;
  __syncthreads();
  float q = 0.f;
#pragma unroll 8
  for (int e = 0; e < 128; ++e) q = fmaf(yl[e], Wq[d * 128 + e], q);
  xl[d] = q;
  __syncthreads();
  float qf = 0.f;
#pragma unroll 8
  for (int e = 0; e < 128; ++e) qf = fmaf(xl[e], f_w2[e * 128 + d], qf);
  float tq = xl[d] * f_b2[d];
  float sq = waveReduceSum(tq);
  if (lane == 0) red[wid] = sq;
  __syncthreads();
  if (d == 0) ws[OFF_QB + bs] = (red[0] + red[1]) * SCALE;
  float offd = -(spl[0] * ws[OFF_GFD + d * 2 + 0] + spl[1] * ws[OFF_GFD + d * 2 + 1]);
  ws[OFF_OQ + (bs * 128 + d) * 2 + 0] = offd;
  ws[OFF_OQ + (bs * 128 + d) * 2 + 1] = qf * SCALE;
}

// ---------------- write outputs ----------------
__global__ __launch_bounds__(256) void kOut(const float* __restrict__ ws,
                                            const float* __restrict__ S_r,
                                            const float* __restrict__ S_s,
                                            float* __restrict__ out) {
  int i = blockIdx.x * 256 + threadIdx.x;
  if (i < 8192) out[i] = ws[OFF_SLOTS + i];
  else if (i < 8320) out[i] = ws[OFF_SP + i - 8192];
  else if (i < 8576) out[i] = S_r[i - 8320];
  else if (i < 8704) out[i] = S_s[i - 8576];
}

extern "C" void kernel_launch(void* const* d_in, const int* in_sizes, int n_in,
                              void* d_out, int out_size, void* d_ws, size_t ws_size,
                              hipStream_t stream) {
  const float* inputs     = (const float*)d_in[0];
  const float* slots_init = (const float*)d_in[1];
  const float* S_p0       = (const float*)d_in[2];
  const float* S_s        = (const float*)d_in[3];
  const float* S_r        = (const float*)d_in[4];
  const float* Wq   = (const float*)d_in[5];
  const float* Wk   = (const float*)d_in[6];
  const float* Wv   = (const float*)d_in[7];
  const float* g_w  = (const float*)d_in[8];
  const float* g_b  = (const float*)d_in[9];
  const float* f_w1 = (const float*)d_in[10];
  const float* f_b1 = (const float*)d_in[11];
  const float* f_w2 = (const float*)d_in[12];
  const float* f_b2 = (const float*)d_in[13];
  const float* gwih = (const float*)d_in[14];
  const float* gwhh = (const float*)d_in[15];
  const float* gbih = (const float*)d_in[16];
  const float* gbhh = (const float*)d_in[17];
  const float* mw1  = (const float*)d_in[18];
  const float* mb1  = (const float*)d_in[19];
  const float* mw2  = (const float*)d_in[20];
  const float* mb2  = (const float*)d_in[21];
  const float* lnsg = (const float*)d_in[22];
  const float* lnsb = (const float*)d_in[23];
  const float* lnpg = (const float*)d_in[24];
  const float* lnpb = (const float*)d_in[25];
  float* ws  = (float*)d_ws;
  float* out = (float*)d_out;

  hipMemcpyAsync(ws + OFF_SLOTS, slots_init, 8192 * sizeof(float),
                 hipMemcpyDeviceToDevice, stream);
  hipMemcpyAsync(ws + OFF_SP, S_p0, 128 * sizeof(float),
                 hipMemcpyDeviceToDevice, stream);
  kCast<<<2048, 256, 0, stream>>>(inputs, ws);
  kFold<<<130, 256, 0, stream>>>(f_w1, Wk, Wv, g_w, g_b, f_b1, ws);
  kBase<<<256, 256, 0, stream>>>(ws);
  kQ<<<64, 128, 0, stream>>>(Wq, f_w2, f_b2, lnsg, lnsb, ws);
  for (int it = 0; it < 3; ++it) {
    kAttn<<<512, 256, 0, stream>>>(ws);
    kCQ<<<64, 128, 0, stream>>>(Wq, f_w2, f_b2, gwih, gwhh, gbih, gbhh,
                                mw1, mb1, mw2, mb2, lnpg, lnpb, lnsg, lnsb, ws);
  }
  kOut<<<34, 256, 0, stream>>>(ws, S_r, S_s, out);
}

// Round 4
// 209.741 us; speedup vs baseline: 1.4780x; 1.1027x over previous
//
#include <hip/hip_runtime.h>
#include <cstdint>
#include <cstddef>

#define SCALE  0.08838834764831845f   // 128^-0.5
#define EPS_   1e-8f
#define LN_EPS_ 1e-5f

typedef unsigned short ushort_t;
typedef unsigned int uint_t;
typedef __attribute__((ext_vector_type(8))) short short8;
typedef __attribute__((ext_vector_type(4))) float f32x4;

// ---------------- workspace layout (float offsets), ~19.2 MB ----------------
constexpr int OFF_GFD   = 0;        // 256   (f_w1@g_w)/DELTA  [h][2]
constexpr int OFF_CB    = 256;      // 128   f_w1@g_b + f_b1
constexpr int OFF_QB    = 384;      // 64
constexpr int OFF_SP    = 448;      // 128
constexpr int OFF_OQ    = 576;      // 16384 interleaved (off, qf*scale)
constexpr int OFF_SLOTS = 16960;    // 8192
constexpr int OFF_ZP    = 25152;    // 4096  [b][64][8]
constexpr int OFF_PP    = 29248;    // 8192  [b][64][8][2]
constexpr int OFF_UP    = 37440;    // 524288 [b][64][8][128]
constexpr int OFF_WKB   = 561728;   // bf16 [128][128] = 8192 float-slots
constexpr int OFF_WVB   = 569920;   // 8192
constexpr int OFF_AB    = 578112;   // bf16 inputs [32768][128] = 2097152 slots
constexpr int OFF_BKT   = 2675264;  // bf16 [b][128][4096] = 1048576 slots
constexpr int OFF_BV    = 3723840;  // bf16 [b][4096][128] = 1048576 slots
constexpr int OFF_FW2T  = 4772416;  // f32 f_w2 transposed [e-major] 16384

__device__ __forceinline__ float waveReduceSum(float v) {
#pragma unroll
  for (int m = 1; m < 64; m <<= 1) v += __shfl_xor(v, m, 64);
  return v;
}
__device__ __forceinline__ float bf2f(uint_t u) { return __uint_as_float(u << 16); }
__device__ __forceinline__ ushort_t f2bf(float f) {
  uint_t u = __float_as_uint(f);
  return (ushort_t)((u + 0x7fffu + ((u >> 16) & 1u)) >> 16);
}

// half-row dot: 16 independent float4 loads (e-range [h*64, h*64+64))
__device__ __forceinline__ float halfDot(const float* __restrict__ Wrow,
                                         const float* xv, int h) {
  const float4* wr = (const float4*)Wrow + h * 16;
  const float4* xr = (const float4*)xv + h * 16;
  float4 a = {0.f, 0.f, 0.f, 0.f};
#pragma unroll
  for (int i = 0; i < 16; ++i) {
    float4 wv = wr[i], xq = xr[i];
    a.x = fmaf(wv.x, xq.x, a.x);
    a.y = fmaf(wv.y, xq.y, a.y);
    a.z = fmaf(wv.z, xq.z, a.z);
    a.w = fmaf(wv.w, xq.w, a.w);
  }
  return (a.x + a.y) + (a.z + a.w);
}

// ---------------- cast inputs f32 -> bf16 ----------------
__global__ __launch_bounds__(256) void kCast(const float* __restrict__ in,
                                             float* __restrict__ ws) {
  int idx = blockIdx.x * 256 + threadIdx.x;      // 0..524287, 8 elems each
  const float4* src = (const float4*)(in + (size_t)idx * 8);
  float4 a = src[0], b = src[1];
  uint_t p0 = (uint_t)f2bf(a.x) | ((uint_t)f2bf(a.y) << 16);
  uint_t p1 = (uint_t)f2bf(a.z) | ((uint_t)f2bf(a.w) << 16);
  uint_t p2 = (uint_t)f2bf(b.x) | ((uint_t)f2bf(b.y) << 16);
  uint_t p3 = (uint_t)f2bf(b.z) | ((uint_t)f2bf(b.w) << 16);
  ((uint4*)((ushort_t*)(ws + OFF_AB)))[idx] = make_uint4(p0, p1, p2, p3);
}

// ---------------- fold weights ----------------
__global__ __launch_bounds__(256) void kFold(
    const float* __restrict__ f_w1, const float* __restrict__ Wk,
    const float* __restrict__ Wv, const float* __restrict__ g_w,
    const float* __restrict__ g_b, const float* __restrict__ f_b1,
    const float* __restrict__ f_w2, float* __restrict__ ws) {
  int blk = blockIdx.x, tid = threadIdx.x;
  if (blk < 128) {
    int isV = blk >> 6;
    int idx = (blk & 63) * 256 + tid;           // 0..16383  (h*128+e)
    int h = idx >> 7, e = idx & 127;
    const float* Wm = isV ? Wv : Wk;
    float a = 0.f;
#pragma unroll 4
    for (int d = 0; d < 128; ++d) a = fmaf(f_w1[h * 128 + d], Wm[d * 128 + e], a);
    ((ushort_t*)(ws + (isV ? OFF_WVB : OFF_WKB)))[idx] = f2bf(a);
  } else if (blk == 128) {
    int h = tid >> 1, c = tid & 1;
    float a = 0.f;
    for (int d = 0; d < 128; ++d) a = fmaf(f_w1[h * 128 + d], g_w[d * 2 + c], a);
    ws[OFF_GFD + tid] = a * 0.2f;               // /DELTA (DELTA=5)
  } else if (blk == 129) {
    if (tid < 128) {
      float a = f_b1[tid];
      for (int d = 0; d < 128; ++d) a = fmaf(f_w1[tid * 128 + d], g_b[d], a);
      ws[OFF_CB + tid] = a;
    }
  } else {
    for (int i = tid; i < 16384; i += 256)
      ws[OFF_FW2T + (i & 127) * 128 + (i >> 7)] = f_w2[i];
  }
}

// ---------------- MFMA base GEMMs ----------------
__global__ __launch_bounds__(256) void kBase(float* __restrict__ ws) {
  __shared__ __align__(16) char smem[32768 + 17408];
  char* wsm = smem;
  char* ep  = smem + 32768;
  const ushort_t* ab = (const ushort_t*)(ws + OFF_AB);
  int tid = threadIdx.x, w = tid >> 6, l = tid & 63;
  int lr = l & 15, lg = l >> 4;
  int blk = blockIdx.x;
  int rowblk = blk * 128;
  int b = blk >> 5;
  int nb_in_b = (blk & 31) * 128;

  short8 afrag[2][4];
#pragma unroll
  for (int rt = 0; rt < 2; ++rt)
#pragma unroll
    for (int ks = 0; ks < 4; ++ks) {
      size_t row = (size_t)rowblk + w * 32 + rt * 16 + lr;
      afrag[rt][ks] = *(const short8*)(ab + row * 128 + ks * 32 + lg * 8);
    }
  float gf0a[8], gf1a[8], cba[8];
#pragma unroll
  for (int ct = 0; ct < 8; ++ct) {
    int c = ct * 16 + lr;
    gf0a[ct] = ws[OFF_GFD + c * 2 + 0];
    gf1a[ct] = ws[OFF_GFD + c * 2 + 1];
    cba[ct]  = ws[OFF_CB + c];
  }
  ushort_t* outK = (ushort_t*)(ws + OFF_BKT);
  ushort_t* outV = (ushort_t*)(ws + OFF_BV);

  for (int mat = 0; mat < 2; ++mat) {
    const uint4* wsrc = (const uint4*)(ws + (mat ? OFF_WVB : OFF_WKB));
    __syncthreads();
    for (int f = tid; f < 2048; f += 256) {
      int c = f >> 4, kg = f & 15;
      int byte = c * 256 + kg * 16;
      *(uint4*)(wsm + (byte ^ ((c & 7) << 4))) = wsrc[f];
    }
    __syncthreads();
    f32x4 acc[2][8];
#pragma unroll
    for (int rt = 0; rt < 2; ++rt)
#pragma unroll
      for (int ct = 0; ct < 8; ++ct) acc[rt][ct] = (f32x4){0.f, 0.f, 0.f, 0.f};
#pragma unroll 2
    for (int ct = 0; ct < 8; ++ct) {
      short8 bfr[4];
#pragma unroll
      for (int ks = 0; ks < 4; ++ks) {
        int c = ct * 16 + lr;
        int byte = c * 256 + ks * 64 + lg * 16;
        bfr[ks] = *(const short8*)(wsm + (byte ^ ((c & 7) << 4)));
      }
#pragma unroll
      for (int ks = 0; ks < 4; ++ks) {
        acc[0][ct] = __builtin_amdgcn_mfma_f32_16x16x32_bf16(afrag[0][ks], bfr[ks], acc[0][ct], 0, 0, 0);
        acc[1][ct] = __builtin_amdgcn_mfma_f32_16x16x32_bf16(afrag[1][ks], bfr[ks], acc[1][ct], 0, 0, 0);
      }
    }
    for (int h = 0; h < 2; ++h) {
      __syncthreads();
      if ((w >> 1) == h) {
        int nl0 = (w & 1) * 32 + lg * 4;
#pragma unroll
        for (int rt = 0; rt < 2; ++rt)
#pragma unroll
          for (int ct = 0; ct < 8; ++ct) {
            int c = ct * 16 + lr;
            ushort_t pk[4];
#pragma unroll
            for (int r = 0; r < 4; ++r) {
              int n = nb_in_b + h * 64 + nl0 + rt * 16 + r;
              float gy = -1.f + (float)(n >> 6) * (2.f / 63.f);
              float gx = -1.f + (float)(n & 63) * (2.f / 63.f);
              float o = acc[rt][ct][r] + gy * gf0a[ct] + gx * gf1a[ct] + cba[ct];
              pk[r] = f2bf(o);
            }
            if (mat == 0) {
              int byte = (c * 128 + (nl0 + rt * 16) * 2) ^ ((c & 7) << 4);
              *(uint2*)(ep + byte) = make_uint2(
                  (uint_t)pk[0] | ((uint_t)pk[1] << 16),
                  (uint_t)pk[2] | ((uint_t)pk[3] << 16));
            } else {
              int rb = nl0 + rt * 16;
#pragma unroll
              for (int r = 0; r < 4; ++r)
                *(ushort_t*)(ep + (rb + r) * 272 + c * 2) = pk[r];
            }
          }
      }
      __syncthreads();
      if (mat == 0) {
        int c = tid >> 1, q = tid & 1;
        size_t gbase = ((size_t)(b * 128 + c)) * 4096 + nb_in_b + h * 64 + q * 32;
#pragma unroll
        for (int i = 0; i < 4; ++i) {
          uint4 v = *(const uint4*)(ep + ((c * 128 + q * 64 + i * 16) ^ ((c & 7) << 4)));
          *(uint4*)(outK + gbase + i * 8) = v;
        }
      } else {
        int nl = tid >> 2, q = tid & 3;
        size_t row = (size_t)rowblk + h * 64 + nl;
#pragma unroll
        for (int i = 0; i < 4; ++i) {
          uint4 v = *(const uint4*)(ep + nl * 272 + q * 64 + i * 16);
          *(uint4*)(outV + row * 128 + q * 32 + i * 8) = v;
        }
      }
    }
  }
}

// ---------------- initial q projection (iteration 0) ----------------
// 256 thr: lane-pair layout, d = w*32 + (lane>>1), h = lane&1 (e-half)
__global__ __launch_bounds__(256) void kQ(
    const float* __restrict__ Wq, const float* __restrict__ f_w2,
    const float* __restrict__ f_b2, const float* __restrict__ lnsg,
    const float* __restrict__ lnsb, float* __restrict__ ws) {
  int bs = blockIdx.x;
  int t = threadIdx.x, w = t >> 6, lane = t & 63;
  int d = w * 32 + (lane >> 1), h = lane & 1;
  __shared__ __align__(16) float yl[128], ql[128];
  __shared__ float red[4], red2[4];
  const float* FW2T = ws + OFF_FW2T;
  float x = ws[OFF_SLOTS + bs * 128 + d];
  float m1 = waveReduceSum(h == 0 ? x : 0.f);
  float m2 = waveReduceSum(h == 0 ? x * x : 0.f);
  if (lane == 0) { red[w] = m1; red2[w] = m2; }
  __syncthreads();
  float mean = (red[0] + red[1] + red[2] + red[3]) * (1.f / 128.f);
  float var = (red2[0] + red2[1] + red2[2] + red2[3]) * (1.f / 128.f) - mean * mean;
  if (h == 0) yl[d] = (x - mean) * rsqrtf(var + LN_EPS_) * lnsg[d] + lnsb[d];
  __syncthreads();
  float q = halfDot(Wq + (size_t)d * 128, yl, h);
  q += __shfl_xor(q, 1, 64);
  if (h == 0) ql[d] = q;
  __syncthreads();
  float qv = waveReduceSum(h == 0 ? q * f_b2[d] : 0.f);
  if (lane == 0) red[w] = qv;
  float qf = halfDot(FW2T + (size_t)d * 128, ql, h);
  qf += __shfl_xor(qf, 1, 64);
  __syncthreads();
  if (t == 0) ws[OFF_QB + bs] = (red[0] + red[1] + red[2] + red[3]) * SCALE;
  if (h == 0) {
    float sp0 = ws[OFF_SP + bs * 2 + 0], sp1 = ws[OFF_SP + bs * 2 + 1];
    float offd = -(sp0 * ws[OFF_GFD + d * 2 + 0] + sp1 * ws[OFF_GFD + d * 2 + 1]);
    ws[OFF_OQ + (bs * 128 + d) * 2 + 0] = offd;
    ws[OFF_OQ + (bs * 128 + d) * 2 + 1] = qf * SCALE;
  }
}

// ---------------- fused attention: 4 waves, d-split / i-split ----------------
__global__ __launch_bounds__(256) void kAttn(float* __restrict__ ws) {
  __shared__ float2 OQl[8][128];
  __shared__ float tp[64][37];
  __shared__ float al[64][13];
  __shared__ float Ush[4][8][132];
  int b = blockIdx.x >> 6, chunk = blockIdx.x & 63;
  int tid = threadIdx.x, w = tid >> 6, lane = tid & 63;
  int sb = b * 8;
  for (int f = tid; f < 1024; f += 256) {
    int s = f >> 7, d = f & 127;
    OQl[s][d] = *(const float2*)&ws[OFF_OQ + ((sb + s) * 128 + d) * 2];
  }
  float qbl[8];
#pragma unroll
  for (int s = 0; s < 8; ++s) qbl[s] = ws[OFF_QB + sb + s];
  __syncthreads();

  int n = chunk * 64 + lane;
  const ushort_t* kp = (const ushort_t*)(ws + OFF_BKT) +
                       (size_t)b * 524288 + (size_t)w * 32 * 4096 + n;
  float t[8];
#pragma unroll
  for (int s = 0; s < 8; ++s) t[s] = 0.f;
#pragma unroll 4
  for (int dd = 0; dd < 32; ++dd) {
    int d = w * 32 + dd;
    float kv = bf2f((uint_t)kp[(size_t)dd * 4096]);
#pragma unroll
    for (int s = 0; s < 8; ++s) {
      float2 oq = OQl[s][d];
      t[s] = fmaf(fmaxf(kv + oq.x, 0.f), oq.y, t[s]);
    }
  }
#pragma unroll
  for (int s = 0; s < 8; ++s) tp[lane][s * 4 + w] = t[s];
  __syncthreads();
  float a[8], den = 0.f;
#pragma unroll
  for (int s = 0; s < 8; ++s)
    t[s] = tp[lane][s * 4 + 0] + tp[lane][s * 4 + 1] +
           tp[lane][s * 4 + 2] + tp[lane][s * 4 + 3] + qbl[s];
  float mx = t[0];
#pragma unroll
  for (int s = 1; s < 8; ++s) mx = fmaxf(mx, t[s]);
#pragma unroll
  for (int s = 0; s < 8; ++s) { a[s] = __expf(t[s] - mx); den += a[s]; }
  float inv = 1.0f / den;
#pragma unroll
  for (int s = 0; s < 8; ++s) a[s] = fmaf(a[s], inv, EPS_);
  if (w == 0) {
    float gy = -1.f + (float)(n >> 6) * (2.f / 63.f);
    float gx = -1.f + (float)(n & 63) * (2.f / 63.f);
#pragma unroll
    for (int s = 0; s < 8; ++s) al[lane][s] = a[s];
#pragma unroll
    for (int s = 0; s < 8; ++s) {
      float z = waveReduceSum(a[s]);
      float p0 = waveReduceSum(a[s] * gy);
      float p1 = waveReduceSum(a[s] * gx);
      if (lane == 0) {
        ws[OFF_ZP + (b * 64 + chunk) * 8 + s] = z;
        ws[OFF_PP + ((b * 64 + chunk) * 8 + s) * 2 + 0] = p0;
        ws[OFF_PP + ((b * 64 + chunk) * 8 + s) * 2 + 1] = p1;
      }
    }
  }
  __syncthreads();

  int c0 = 2 * lane;
  float offv0[8], offv1[8];
#pragma unroll
  for (int s = 0; s < 8; ++s) {
    offv0[s] = OQl[s][c0].x;
    offv1[s] = OQl[s][c0 + 1].x;
  }
  float Ua0[8], Ua1[8];
#pragma unroll
  for (int s = 0; s < 8; ++s) { Ua0[s] = 0.f; Ua1[s] = 0.f; }
  const ushort_t* vp = (const ushort_t*)(ws + OFF_BV) +
                       ((size_t)(b * 4096 + chunk * 64 + w * 16)) * 128 + c0;
#pragma unroll 4
  for (int i = 0; i < 16; ++i) {
    uint_t vraw = *(const uint_t*)(vp + (size_t)i * 128);
    float v0 = bf2f(vraw & 0xffffu);
    float v1 = bf2f(vraw >> 16);
    int ii = w * 16 + i;
#pragma unroll
    for (int s = 0; s < 8; ++s) {
      float as = al[ii][s];
      Ua0[s] = fmaf(as, fmaxf(v0 + offv0[s], 0.f), Ua0[s]);
      Ua1[s] = fmaf(as, fmaxf(v1 + offv1[s], 0.f), Ua1[s]);
    }
  }
#pragma unroll
  for (int s = 0; s < 8; ++s)
    *(float2*)&Ush[w][s][c0] = make_float2(Ua0[s], Ua1[s]);
  __syncthreads();
  for (int f = tid; f < 1024; f += 256) {
    int s = f >> 7, c = f & 127;
    float v = Ush[0][s][c] + Ush[1][s][c] + Ush[2][s][c] + Ush[3][s][c];
    ws[OFF_UP + ((size_t)(b * 64 + chunk) * 8 + s) * 128 + c] = v;
  }
}

// ---------------- fused: finalize + GRU + post-MLP + next-iter q ----------------
// 256 thr, lane-pair split-e layout
__global__ __launch_bounds__(256) void kCQ(
    const float* __restrict__ Wq, const float* __restrict__ f_w2,
    const float* __restrict__ f_b2, const float* __restrict__ wih,
    const float* __restrict__ whh, const float* __restrict__ bih,
    const float* __restrict__ bhh, const float* __restrict__ mw1,
    const float* __restrict__ mb1, const float* __restrict__ mw2,
    const float* __restrict__ mb2, const float* __restrict__ lnpg,
    const float* __restrict__ lnpb, const float* __restrict__ lnsg,
    const float* __restrict__ lnsb, float* __restrict__ ws) {
  int bs = blockIdx.x, b = bs >> 3, s = bs & 7;
  int t = threadIdx.x, w = t >> 6, lane = t & 63;
  int d = w * 32 + (lane >> 1), h = lane & 1;
  __shared__ __align__(16) float ul[128], xl[128], sl[128], yl[128], hml[128];
  __shared__ float red[4], red2[4];
  const float* FW2T = ws + OFF_FW2T;
  // Z, P (redundant per wave: lane <-> chunk)
  float zv = ws[OFF_ZP + (b * 64 + lane) * 8 + s];
  float2 pv = *(const float2*)&ws[OFF_PP + ((size_t)(b * 64 + lane) * 8 + s) * 2];
  float Z = waveReduceSum(zv);
  float P0 = waveReduceSum(pv.x);
  float P1 = waveReduceSum(pv.y);
  float invZ = 1.f / Z, sp0 = P0 * invZ, sp1 = P1 * invZ;
  // U partial: this thread's 32 chunks
  float u = 0.f;
  const float* up = ws + OFF_UP + ((size_t)(b * 64 + h * 32) * 8 + s) * 128 + d;
#pragma unroll 8
  for (int ch = 0; ch < 32; ++ch) u += up[(size_t)ch * 1024];
  u += __shfl_xor(u, 1, 64);
  if (h == 0) { ul[d] = u * invZ; sl[d] = ws[OFF_SLOTS + bs * 128 + d]; }
  if (t == 0) { ws[OFF_SP + bs * 2 + 0] = sp0; ws[OFF_SP + bs * 2 + 1] = sp1; }
  __syncthreads();
  // updates through f_w2
  float xa = halfDot(f_w2 + (size_t)d * 128, ul, h);
  xa += __shfl_xor(xa, 1, 64);
  if (h == 0) xl[d] = xa + f_b2[d];
  __syncthreads();
  // GRU: 6 half-row dots
  float ir = halfDot(wih + (size_t)d * 128, xl, h);
  float iz = halfDot(wih + (size_t)(128 + d) * 128, xl, h);
  float in_ = halfDot(wih + (size_t)(256 + d) * 128, xl, h);
  float hr = halfDot(whh + (size_t)d * 128, sl, h);
  float hz = halfDot(whh + (size_t)(128 + d) * 128, sl, h);
  float hn = halfDot(whh + (size_t)(256 + d) * 128, sl, h);
  ir += __shfl_xor(ir, 1, 64);
  iz += __shfl_xor(iz, 1, 64);
  in_ += __shfl_xor(in_, 1, 64);
  hr += __shfl_xor(hr, 1, 64);
  hz += __shfl_xor(hz, 1, 64);
  hn += __shfl_xor(hn, 1, 64);
  float hnew = 0.f;
  if (h == 0) {
    float rg = 1.f / (1.f + __expf(-(ir + bih[d] + hr + bhh[d])));
    float zg = 1.f / (1.f + __expf(-(iz + bih[128 + d] + hz + bhh[128 + d])));
    float ng = tanhf(in_ + bih[256 + d] + rg * (hn + bhh[256 + d]));
    hnew = (1.f - zg) * ng + zg * sl[d];
  }
  // LN_pf (one-pass mean/var)
  float m1 = waveReduceSum(h == 0 ? hnew : 0.f);
  float m2 = waveReduceSum(h == 0 ? hnew * hnew : 0.f);
  if (lane == 0) { red[w] = m1; red2[w] = m2; }
  __syncthreads();
  float mean = (red[0] + red[1] + red[2] + red[3]) * (1.f / 128.f);
  float var = (red2[0] + red2[1] + red2[2] + red2[3]) * (1.f / 128.f) - mean * mean;
  if (h == 0) yl[d] = (hnew - mean) * rsqrtf(var + LN_EPS_) * lnpg[d] + lnpb[d];
  __syncthreads();
  // post-MLP
  float hm = halfDot(mw1 + (size_t)d * 128, yl, h);
  hm += __shfl_xor(hm, 1, 64);
  if (h == 0) hml[d] = fmaxf(hm + mb1[d], 0.f);
  __syncthreads();
  float oa = halfDot(mw2 + (size_t)d * 128, hml, h);
  oa += __shfl_xor(oa, 1, 64);
  float o = 0.f;
  if (h == 0) {
    o = hnew + mb2[d] + oa;
    ws[OFF_SLOTS + bs * 128 + d] = o;
  }
  // LN_s(o) for next-iter q
  float n1 = waveReduceSum(h == 0 ? o : 0.f);
  float n2 = waveReduceSum(h == 0 ? o * o : 0.f);
  if (lane == 0) { red[w] = n1; red2[w] = n2; }
  __syncthreads();
  float mean2 = (red[0] + red[1] + red[2] + red[3]) * (1.f / 128.f);
  float var2 = (red2[0] + red2[1] + red2[2] + red2[3]) * (1.f / 128.f) - mean2 * mean2;
  if (h == 0) yl[d] = (o - mean2) * rsqrtf(var2 + LN_EPS_) * lnsg[d] + lnsb[d];
  __syncthreads();
  float q = halfDot(Wq + (size_t)d * 128, yl, h);
  q += __shfl_xor(q, 1, 64);
  if (h == 0) xl[d] = q;      // reuse xl as q-vector
  __syncthreads();
  float qv = waveReduceSum(h == 0 ? q * f_b2[d] : 0.f);
  if (lane == 0) red[w] = qv;
  float qf = halfDot(FW2T + (size_t)d * 128, xl, h);
  qf += __shfl_xor(qf, 1, 64);
  __syncthreads();
  if (t == 0) ws[OFF_QB + bs] = (red[0] + red[1] + red[2] + red[3]) * SCALE;
  if (h == 0) {
    float offd = -(sp0 * ws[OFF_GFD + d * 2 + 0] + sp1 * ws[OFF_GFD + d * 2 + 1]);
    ws[OFF_OQ + (bs * 128 + d) * 2 + 0] = offd;
    ws[OFF_OQ + (bs * 128 + d) * 2 + 1] = qf * SCALE;
  }
}

// ---------------- write outputs ----------------
__global__ __launch_bounds__(256) void kOut(const float* __restrict__ ws,
                                            const float* __restrict__ S_r,
                                            const float* __restrict__ S_s,
                                            float* __restrict__ out) {
  int i = blockIdx.x * 256 + threadIdx.x;
  if (i < 8192) out[i] = ws[OFF_SLOTS + i];
  else if (i < 8320) out[i] = ws[OFF_SP + i - 8192];
  else if (i < 8576) out[i] = S_r[i - 8320];
  else if (i < 8704) out[i] = S_s[i - 8576];
}

extern "C" void kernel_launch(void* const* d_in, const int* in_sizes, int n_in,
                              void* d_out, int out_size, void* d_ws, size_t ws_size,
                              hipStream_t stream) {
  const float* inputs     = (const float*)d_in[0];
  const float* slots_init = (const float*)d_in[1];
  const float* S_p0       = (const float*)d_in[2];
  const float* S_s        = (const float*)d_in[3];
  const float* S_r        = (const float*)d_in[4];
  const float* Wq   = (const float*)d_in[5];
  const float* Wk   = (const float*)d_in[6];
  const float* Wv   = (const float*)d_in[7];
  const float* g_w  = (const float*)d_in[8];
  const float* g_b  = (const float*)d_in[9];
  const float* f_w1 = (const float*)d_in[10];
  const float* f_b1 = (const float*)d_in[11];
  const float* f_w2 = (const float*)d_in[12];
  const float* f_b2 = (const float*)d_in[13];
  const float* gwih = (const float*)d_in[14];
  const float* gwhh = (const float*)d_in[15];
  const float* gbih = (const float*)d_in[16];
  const float* gbhh = (const float*)d_in[17];
  const float* mw1  = (const float*)d_in[18];
  const float* mb1  = (const float*)d_in[19];
  const float* mw2  = (const float*)d_in[20];
  const float* mb2  = (const float*)d_in[21];
  const float* lnsg = (const float*)d_in[22];
  const float* lnsb = (const float*)d_in[23];
  const float* lnpg = (const float*)d_in[24];
  const float* lnpb = (const float*)d_in[25];
  float* ws  = (float*)d_ws;
  float* out = (float*)d_out;

  hipMemcpyAsync(ws + OFF_SLOTS, slots_init, 8192 * sizeof(float),
                 hipMemcpyDeviceToDevice, stream);
  hipMemcpyAsync(ws + OFF_SP, S_p0, 128 * sizeof(float),
                 hipMemcpyDeviceToDevice, stream);
  kCast<<<2048, 256, 0, stream>>>(inputs, ws);
  kFold<<<131, 256, 0, stream>>>(f_w1, Wk, Wv, g_w, g_b, f_b1, f_w2, ws);
  kBase<<<256, 256, 0, stream>>>(ws);
  kQ<<<64, 256, 0, stream>>>(Wq, f_w2, f_b2, lnsg, lnsb, ws);
  for (int it = 0; it < 3; ++it) {
    kAttn<<<512, 256, 0, stream>>>(ws);
    kCQ<<<64, 256, 0, stream>>>(Wq, f_w2, f_b2, gwih, gwhh, gbih, gbhh,
                                mw1, mb1, mw2, mb2, lnpg, lnpb, lnsg, lnsb, ws);
  }
  kOut<<<34, 256, 0, stream>>>(ws, S_r, S_s, out);
}

// Round 5
// 200.576 us; speedup vs baseline: 1.5455x; 1.0457x over previous
//
#include <hip/hip_runtime.h>
#include <cstdint>
#include <cstddef>

#define SCALE  0.08838834764831845f   // 128^-0.5
#define EPS_   1e-8f
#define LN_EPS_ 1e-5f

typedef unsigned short ushort_t;
typedef unsigned int uint_t;
typedef __attribute__((ext_vector_type(8))) short short8;
typedef __attribute__((ext_vector_type(4))) float f32x4;

// ---------------- workspace layout (float offsets), ~19.2 MB ----------------
constexpr int OFF_GFD   = 0;        // 256   (f_w1@g_w)/DELTA  [h][2]
constexpr int OFF_CB    = 256;      // 128   f_w1@g_b + f_b1
constexpr int OFF_QB    = 384;      // 64
constexpr int OFF_SP    = 448;      // 128
constexpr int OFF_OQ    = 576;      // 16384 interleaved (off, qf*scale)
constexpr int OFF_SLOTS = 16960;    // 8192
constexpr int OFF_ZP    = 25152;    // 4096  [b][64][8]
constexpr int OFF_PP    = 29248;    // 8192  [b][64][8][2]
constexpr int OFF_UP    = 37440;    // 524288 [b][64][8][128]
constexpr int OFF_WKB   = 561728;   // bf16 [128][128] = 8192 float-slots
constexpr int OFF_WVB   = 569920;   // 8192
constexpr int OFF_AB    = 578112;   // bf16 inputs [32768][128] = 2097152 slots
constexpr int OFF_BKT   = 2675264;  // bf16 [b][128][4096] = 1048576 slots
constexpr int OFF_BV    = 3723840;  // bf16 [b][4096][128] = 1048576 slots
constexpr int OFF_FW2T  = 4772416;  // f32 f_w2 transposed [e-major] 16384

__device__ __forceinline__ float waveReduceSum(float v) {
#pragma unroll
  for (int m = 1; m < 64; m <<= 1) v += __shfl_xor(v, m, 64);
  return v;
}
__device__ __forceinline__ float bf2f(uint_t u) { return __uint_as_float(u << 16); }
__device__ __forceinline__ ushort_t f2bf(float f) {
  uint_t u = __float_as_uint(f);
  return (ushort_t)((u + 0x7fffu + ((u >> 16) & 1u)) >> 16);
}

// half-row dot (e-range [h*64, h*64+64)), 16 independent float4 loads
__device__ __forceinline__ float halfDot(const float* __restrict__ Wrow,
                                         const float* xv, int h) {
  const float4* wr = (const float4*)Wrow + h * 16;
  const float4* xr = (const float4*)xv + h * 16;
  float4 a = {0.f, 0.f, 0.f, 0.f};
#pragma unroll
  for (int i = 0; i < 16; ++i) {
    float4 wv = wr[i], xq = xr[i];
    a.x = fmaf(wv.x, xq.x, a.x);
    a.y = fmaf(wv.y, xq.y, a.y);
    a.z = fmaf(wv.z, xq.z, a.z);
    a.w = fmaf(wv.w, xq.w, a.w);
  }
  return (a.x + a.y) + (a.z + a.w);
}

// quarter-row dot (e-range [h*32, h*32+32)), 8 independent float4 loads
__device__ __forceinline__ float quarterDot(const float* __restrict__ Wrow,
                                            const float* xv, int h) {
  const float4* wr = (const float4*)Wrow + h * 8;
  const float4* xr = (const float4*)xv + h * 8;
  float4 a = {0.f, 0.f, 0.f, 0.f};
#pragma unroll
  for (int i = 0; i < 8; ++i) {
    float4 wv = wr[i], xq = xr[i];
    a.x = fmaf(wv.x, xq.x, a.x);
    a.y = fmaf(wv.y, xq.y, a.y);
    a.z = fmaf(wv.z, xq.z, a.z);
    a.w = fmaf(wv.w, xq.w, a.w);
  }
  return (a.x + a.y) + (a.z + a.w);
}
// combine 4-lane partial (lanes differ in bits 0..1)
__device__ __forceinline__ float quadSum(float v) {
  v += __shfl_xor(v, 1, 64);
  v += __shfl_xor(v, 2, 64);
  return v;
}

// ---------------- cast inputs f32 -> bf16 ----------------
__global__ __launch_bounds__(256) void kCast(const float* __restrict__ in,
                                             float* __restrict__ ws) {
  int idx = blockIdx.x * 256 + threadIdx.x;      // 0..524287, 8 elems each
  const float4* src = (const float4*)(in + (size_t)idx * 8);
  float4 a = src[0], b = src[1];
  uint_t p0 = (uint_t)f2bf(a.x) | ((uint_t)f2bf(a.y) << 16);
  uint_t p1 = (uint_t)f2bf(a.z) | ((uint_t)f2bf(a.w) << 16);
  uint_t p2 = (uint_t)f2bf(b.x) | ((uint_t)f2bf(b.y) << 16);
  uint_t p3 = (uint_t)f2bf(b.z) | ((uint_t)f2bf(b.w) << 16);
  ((uint4*)((ushort_t*)(ws + OFF_AB)))[idx] = make_uint4(p0, p1, p2, p3);
}

// ---------------- fold weights ----------------
__global__ __launch_bounds__(256) void kFold(
    const float* __restrict__ f_w1, const float* __restrict__ Wk,
    const float* __restrict__ Wv, const float* __restrict__ g_w,
    const float* __restrict__ g_b, const float* __restrict__ f_b1,
    const float* __restrict__ f_w2, float* __restrict__ ws) {
  int blk = blockIdx.x, tid = threadIdx.x;
  if (blk < 128) {
    int isV = blk >> 6;
    int idx = (blk & 63) * 256 + tid;           // 0..16383  (h*128+e)
    int h = idx >> 7, e = idx & 127;
    const float* Wm = isV ? Wv : Wk;
    float a = 0.f;
#pragma unroll 4
    for (int d = 0; d < 128; ++d) a = fmaf(f_w1[h * 128 + d], Wm[d * 128 + e], a);
    ((ushort_t*)(ws + (isV ? OFF_WVB : OFF_WKB)))[idx] = f2bf(a);
  } else if (blk == 128) {
    int h = tid >> 1, c = tid & 1;
    float a = 0.f;
    for (int d = 0; d < 128; ++d) a = fmaf(f_w1[h * 128 + d], g_w[d * 2 + c], a);
    ws[OFF_GFD + tid] = a * 0.2f;               // /DELTA (DELTA=5)
  } else if (blk == 129) {
    if (tid < 128) {
      float a = f_b1[tid];
      for (int d = 0; d < 128; ++d) a = fmaf(f_w1[tid * 128 + d], g_b[d], a);
      ws[OFF_CB + tid] = a;
    }
  } else {
    for (int i = tid; i < 16384; i += 256)
      ws[OFF_FW2T + (i & 127) * 128 + (i >> 7)] = f_w2[i];
  }
}

// ---------------- MFMA base GEMMs ----------------
// grid (256 rowblocks, 2 mats), 256 thr. B-frags straight from L2-resident W.
__global__ __launch_bounds__(256) void kBase(float* __restrict__ ws) {
  __shared__ __align__(16) char ep[17408];      // epilogue transpose buffer
  const ushort_t* ab = (const ushort_t*)(ws + OFF_AB);
  int tid = threadIdx.x, w = tid >> 6, l = tid & 63;
  int lr = l & 15, lg = l >> 4;
  int mat = blockIdx.y;
  int rowblk = blockIdx.x * 128;
  int b = blockIdx.x >> 5;
  int nb_in_b = (blockIdx.x & 31) * 128;
  const ushort_t* Wg = (const ushort_t*)(ws + (mat ? OFF_WVB : OFF_WKB));

  short8 afrag[2][4];
#pragma unroll
  for (int rt = 0; rt < 2; ++rt)
#pragma unroll
    for (int ks = 0; ks < 4; ++ks) {
      size_t row = (size_t)rowblk + w * 32 + rt * 16 + lr;
      afrag[rt][ks] = *(const short8*)(ab + row * 128 + ks * 32 + lg * 8);
    }
  float gf0a[8], gf1a[8], cba[8];
#pragma unroll
  for (int ct = 0; ct < 8; ++ct) {
    int c = ct * 16 + lr;
    gf0a[ct] = ws[OFF_GFD + c * 2 + 0];
    gf1a[ct] = ws[OFF_GFD + c * 2 + 1];
    cba[ct]  = ws[OFF_CB + c];
  }
  f32x4 acc[2][8];
#pragma unroll
  for (int rt = 0; rt < 2; ++rt)
#pragma unroll
    for (int ct = 0; ct < 8; ++ct) acc[rt][ct] = (f32x4){0.f, 0.f, 0.f, 0.f};
#pragma unroll 2
  for (int ct = 0; ct < 8; ++ct) {
    short8 bfr[4];
#pragma unroll
    for (int ks = 0; ks < 4; ++ks)
      bfr[ks] = *(const short8*)(Wg + (ct * 16 + lr) * 128 + ks * 32 + lg * 8);
#pragma unroll
    for (int ks = 0; ks < 4; ++ks) {
      acc[0][ct] = __builtin_amdgcn_mfma_f32_16x16x32_bf16(afrag[0][ks], bfr[ks], acc[0][ct], 0, 0, 0);
      acc[1][ct] = __builtin_amdgcn_mfma_f32_16x16x32_bf16(afrag[1][ks], bfr[ks], acc[1][ct], 0, 0, 0);
    }
  }
  ushort_t* outK = (ushort_t*)(ws + OFF_BKT);
  ushort_t* outV = (ushort_t*)(ws + OFF_BV);
  // epilogue: two 64-row halves through LDS transpose buffer
  for (int h = 0; h < 2; ++h) {
    __syncthreads();
    if ((w >> 1) == h) {
      int nl0 = (w & 1) * 32 + lg * 4;
#pragma unroll
      for (int rt = 0; rt < 2; ++rt)
#pragma unroll
        for (int ct = 0; ct < 8; ++ct) {
          int c = ct * 16 + lr;
          ushort_t pk[4];
#pragma unroll
          for (int r = 0; r < 4; ++r) {
            int n = nb_in_b + h * 64 + nl0 + rt * 16 + r;
            float gy = -1.f + (float)(n >> 6) * (2.f / 63.f);
            float gx = -1.f + (float)(n & 63) * (2.f / 63.f);
            float o = acc[rt][ct][r] + gy * gf0a[ct] + gx * gf1a[ct] + cba[ct];
            pk[r] = f2bf(o);
          }
          if (mat == 0) {    // epK: [c:128][n:64] bf16 rows of 128B, swizzled
            int byte = (c * 128 + (nl0 + rt * 16) * 2) ^ ((c & 7) << 4);
            *(uint2*)(ep + byte) = make_uint2(
                (uint_t)pk[0] | ((uint_t)pk[1] << 16),
                (uint_t)pk[2] | ((uint_t)pk[3] << 16));
          } else {           // epV: [n:64][c pad 136] bf16 rows of 272B
            int rb = nl0 + rt * 16;
#pragma unroll
            for (int r = 0; r < 4; ++r)
              *(ushort_t*)(ep + (rb + r) * 272 + c * 2) = pk[r];
          }
        }
    }
    __syncthreads();
    if (mat == 0) {          // store: 8 lanes cover one c-row's 128B segment
      for (int idx = tid; idx < 1024; idx += 256) {
        int c = idx >> 3, j = idx & 7;
        uint4 v = *(const uint4*)(ep + ((c * 128 + j * 16) ^ ((c & 7) << 4)));
        *(uint4*)(outK + ((size_t)(b * 128 + c)) * 4096 + nb_in_b + h * 64 + j * 8) = v;
      }
    } else {                 // store: 16 lanes cover one n-row's 256B
      for (int idx = tid; idx < 1024; idx += 256) {
        int nl = idx >> 4, j = idx & 15;
        uint4 v = *(const uint4*)(ep + nl * 272 + j * 16);
        *(uint4*)(outV + ((size_t)rowblk + h * 64 + nl) * 128 + j * 8) = v;
      }
    }
  }
}

// ---------------- initial q projection (iteration 0) ----------------
__global__ __launch_bounds__(256) void kQ(
    const float* __restrict__ Wq, const float* __restrict__ f_w2,
    const float* __restrict__ f_b2, const float* __restrict__ lnsg,
    const float* __restrict__ lnsb, float* __restrict__ ws) {
  int bs = blockIdx.x;
  int t = threadIdx.x, w = t >> 6, lane = t & 63;
  int d = w * 32 + (lane >> 1), h = lane & 1;
  __shared__ __align__(16) float yl[128], ql[128];
  __shared__ float red[4], red2[4];
  const float* FW2T = ws + OFF_FW2T;
  float x = ws[OFF_SLOTS + bs * 128 + d];
  float m1 = waveReduceSum(h == 0 ? x : 0.f);
  float m2 = waveReduceSum(h == 0 ? x * x : 0.f);
  if (lane == 0) { red[w] = m1; red2[w] = m2; }
  __syncthreads();
  float mean = (red[0] + red[1] + red[2] + red[3]) * (1.f / 128.f);
  float var = (red2[0] + red2[1] + red2[2] + red2[3]) * (1.f / 128.f) - mean * mean;
  if (h == 0) yl[d] = (x - mean) * rsqrtf(var + LN_EPS_) * lnsg[d] + lnsb[d];
  __syncthreads();
  float q = halfDot(Wq + (size_t)d * 128, yl, h);
  q += __shfl_xor(q, 1, 64);
  if (h == 0) ql[d] = q;
  __syncthreads();
  float qv = waveReduceSum(h == 0 ? q * f_b2[d] : 0.f);
  if (lane == 0) red[w] = qv;
  float qf = halfDot(FW2T + (size_t)d * 128, ql, h);
  qf += __shfl_xor(qf, 1, 64);
  __syncthreads();
  if (t == 0) ws[OFF_QB + bs] = (red[0] + red[1] + red[2] + red[3]) * SCALE;
  if (h == 0) {
    float sp0 = ws[OFF_SP + bs * 2 + 0], sp1 = ws[OFF_SP + bs * 2 + 1];
    float offd = -(sp0 * ws[OFF_GFD + d * 2 + 0] + sp1 * ws[OFF_GFD + d * 2 + 1]);
    ws[OFF_OQ + (bs * 128 + d) * 2 + 0] = offd;
    ws[OFF_OQ + (bs * 128 + d) * 2 + 1] = qf * SCALE;
  }
}

// ---------------- fused attention: 4 waves, d-split / i-split ----------------
__global__ __launch_bounds__(256) void kAttn(float* __restrict__ ws) {
  __shared__ float2 OQl[8][128];
  __shared__ float tp[64][37];
  __shared__ float al[64][13];
  __shared__ float Ush[4][8][132];
  int b = blockIdx.x >> 6, chunk = blockIdx.x & 63;
  int tid = threadIdx.x, w = tid >> 6, lane = tid & 63;
  int sb = b * 8;
  for (int f = tid; f < 1024; f += 256) {
    int s = f >> 7, d = f & 127;
    OQl[s][d] = *(const float2*)&ws[OFF_OQ + ((sb + s) * 128 + d) * 2];
  }
  float qbl[8];
#pragma unroll
  for (int s = 0; s < 8; ++s) qbl[s] = ws[OFF_QB + sb + s];
  __syncthreads();

  int n = chunk * 64 + lane;
  const ushort_t* kp = (const ushort_t*)(ws + OFF_BKT) +
                       (size_t)b * 524288 + (size_t)w * 32 * 4096 + n;
  float t[8];
#pragma unroll
  for (int s = 0; s < 8; ++s) t[s] = 0.f;
#pragma unroll 4
  for (int dd = 0; dd < 32; ++dd) {
    int d = w * 32 + dd;
    float kv = bf2f((uint_t)kp[(size_t)dd * 4096]);
#pragma unroll
    for (int s = 0; s < 8; ++s) {
      float2 oq = OQl[s][d];
      t[s] = fmaf(fmaxf(kv + oq.x, 0.f), oq.y, t[s]);
    }
  }
#pragma unroll
  for (int s = 0; s < 8; ++s) tp[lane][s * 4 + w] = t[s];
  __syncthreads();
  float a[8], den = 0.f;
#pragma unroll
  for (int s = 0; s < 8; ++s)
    t[s] = tp[lane][s * 4 + 0] + tp[lane][s * 4 + 1] +
           tp[lane][s * 4 + 2] + tp[lane][s * 4 + 3] + qbl[s];
  float mx = t[0];
#pragma unroll
  for (int s = 1; s < 8; ++s) mx = fmaxf(mx, t[s]);
#pragma unroll
  for (int s = 0; s < 8; ++s) { a[s] = __expf(t[s] - mx); den += a[s]; }
  float inv = 1.0f / den;
#pragma unroll
  for (int s = 0; s < 8; ++s) a[s] = fmaf(a[s], inv, EPS_);
  if (w == 0) {
    float gy = -1.f + (float)(n >> 6) * (2.f / 63.f);
    float gx = -1.f + (float)(n & 63) * (2.f / 63.f);
#pragma unroll
    for (int s = 0; s < 8; ++s) al[lane][s] = a[s];
#pragma unroll
    for (int s = 0; s < 8; ++s) {
      float z = waveReduceSum(a[s]);
      float p0 = waveReduceSum(a[s] * gy);
      float p1 = waveReduceSum(a[s] * gx);
      if (lane == 0) {
        ws[OFF_ZP + (b * 64 + chunk) * 8 + s] = z;
        ws[OFF_PP + ((b * 64 + chunk) * 8 + s) * 2 + 0] = p0;
        ws[OFF_PP + ((b * 64 + chunk) * 8 + s) * 2 + 1] = p1;
      }
    }
  }
  __syncthreads();

  int c0 = 2 * lane;
  float offv0[8], offv1[8];
#pragma unroll
  for (int s = 0; s < 8; ++s) {
    offv0[s] = OQl[s][c0].x;
    offv1[s] = OQl[s][c0 + 1].x;
  }
  float Ua0[8], Ua1[8];
#pragma unroll
  for (int s = 0; s < 8; ++s) { Ua0[s] = 0.f; Ua1[s] = 0.f; }
  const ushort_t* vp = (const ushort_t*)(ws + OFF_BV) +
                       ((size_t)(b * 4096 + chunk * 64 + w * 16)) * 128 + c0;
#pragma unroll 4
  for (int i = 0; i < 16; ++i) {
    uint_t vraw = *(const uint_t*)(vp + (size_t)i * 128);
    float v0 = bf2f(vraw & 0xffffu);
    float v1 = bf2f(vraw >> 16);
    int ii = w * 16 + i;
#pragma unroll
    for (int s = 0; s < 8; ++s) {
      float as = al[ii][s];
      Ua0[s] = fmaf(as, fmaxf(v0 + offv0[s], 0.f), Ua0[s]);
      Ua1[s] = fmaf(as, fmaxf(v1 + offv1[s], 0.f), Ua1[s]);
    }
  }
#pragma unroll
  for (int s = 0; s < 8; ++s)
    *(float2*)&Ush[w][s][c0] = make_float2(Ua0[s], Ua1[s]);
  __syncthreads();
  for (int f = tid; f < 1024; f += 256) {
    int s = f >> 7, c = f & 127;
    float v = Ush[0][s][c] + Ush[1][s][c] + Ush[2][s][c] + Ush[3][s][c];
    ws[OFF_UP + ((size_t)(b * 64 + chunk) * 8 + s) * 128 + c] = v;
  }
}

// ---------------- fused: finalize + GRU + post-MLP + next-iter q ----------------
// 512 thr: d = t>>2 (0..127), h = t&3 (e-quarter)
__global__ __launch_bounds__(512) void kCQ(
    const float* __restrict__ Wq, const float* __restrict__ f_w2,
    const float* __restrict__ f_b2, const float* __restrict__ wih,
    const float* __restrict__ whh, const float* __restrict__ bih,
    const float* __restrict__ bhh, const float* __restrict__ mw1,
    const float* __restrict__ mb1, const float* __restrict__ mw2,
    const float* __restrict__ mb2, const float* __restrict__ lnpg,
    const float* __restrict__ lnpb, const float* __restrict__ lnsg,
    const float* __restrict__ lnsb, float* __restrict__ ws) {
  int bs = blockIdx.x, b = bs >> 3, s = bs & 7;
  int t = threadIdx.x, w = t >> 6, lane = t & 63;
  int d = t >> 2, h = t & 3;
  __shared__ __align__(16) float ul[128], xl[128], sl[128], yl[128], hml[128];
  __shared__ float red[8], red2[8];
  const float* FW2T = ws + OFF_FW2T;
  // Z, P: each wave redundantly reduces the 64 chunk partials (lane=chunk)
  float zv = ws[OFF_ZP + (b * 64 + lane) * 8 + s];
  float2 pv = *(const float2*)&ws[OFF_PP + ((size_t)(b * 64 + lane) * 8 + s) * 2];
  float Z = waveReduceSum(zv);
  float P0 = waveReduceSum(pv.x);
  float P1 = waveReduceSum(pv.y);
  float invZ = 1.f / Z, sp0 = P0 * invZ, sp1 = P1 * invZ;
  // U partial: thread (d,h) sums its 16 chunks
  float u = 0.f;
  const float* up = ws + OFF_UP + ((size_t)(b * 64 + h * 16) * 8 + s) * 128 + d;
#pragma unroll
  for (int ch = 0; ch < 16; ++ch) u += up[(size_t)ch * 1024];
  u = quadSum(u);
  if (h == 0) { ul[d] = u * invZ; sl[d] = ws[OFF_SLOTS + bs * 128 + d]; }
  if (t == 0) { ws[OFF_SP + bs * 2 + 0] = sp0; ws[OFF_SP + bs * 2 + 1] = sp1; }
  __syncthreads();
  // updates through f_w2
  float xa = quadSum(quarterDot(f_w2 + (size_t)d * 128, ul, h));
  if (h == 0) xl[d] = xa + f_b2[d];
  __syncthreads();
  // GRU: 6 quarter-row dots (independent -> deep ILP)
  float ir = quarterDot(wih + (size_t)d * 128, xl, h);
  float iz = quarterDot(wih + (size_t)(128 + d) * 128, xl, h);
  float in_ = quarterDot(wih + (size_t)(256 + d) * 128, xl, h);
  float hr = quarterDot(whh + (size_t)d * 128, sl, h);
  float hz = quarterDot(whh + (size_t)(128 + d) * 128, sl, h);
  float hn = quarterDot(whh + (size_t)(256 + d) * 128, sl, h);
  ir = quadSum(ir); iz = quadSum(iz); in_ = quadSum(in_);
  hr = quadSum(hr); hz = quadSum(hz); hn = quadSum(hn);
  float hnew = 0.f;
  if (h == 0) {
    float rg = 1.f / (1.f + __expf(-(ir + bih[d] + hr + bhh[d])));
    float zg = 1.f / (1.f + __expf(-(iz + bih[128 + d] + hz + bhh[128 + d])));
    float ng = tanhf(in_ + bih[256 + d] + rg * (hn + bhh[256 + d]));
    hnew = (1.f - zg) * ng + zg * sl[d];
  }
  // LN_pf
  float m1 = waveReduceSum(h == 0 ? hnew : 0.f);
  float m2 = waveReduceSum(h == 0 ? hnew * hnew : 0.f);
  if (lane == 0) { red[w] = m1; red2[w] = m2; }
  __syncthreads();
  float mean = 0.f, var = 0.f;
#pragma unroll
  for (int i = 0; i < 8; ++i) { mean += red[i]; var += red2[i]; }
  mean *= (1.f / 128.f);
  var = var * (1.f / 128.f) - mean * mean;
  if (h == 0) yl[d] = (hnew - mean) * rsqrtf(var + LN_EPS_) * lnpg[d] + lnpb[d];
  __syncthreads();
  // post-MLP
  float hm = quadSum(quarterDot(mw1 + (size_t)d * 128, yl, h));
  if (h == 0) hml[d] = fmaxf(hm + mb1[d], 0.f);
  __syncthreads();
  float oa = quadSum(quarterDot(mw2 + (size_t)d * 128, hml, h));
  float o = 0.f;
  if (h == 0) {
    o = hnew + mb2[d] + oa;
    ws[OFF_SLOTS + bs * 128 + d] = o;
  }
  // LN_s(o) for next-iter q
  float n1 = waveReduceSum(h == 0 ? o : 0.f);
  float n2 = waveReduceSum(h == 0 ? o * o : 0.f);
  if (lane == 0) { red[w] = n1; red2[w] = n2; }
  __syncthreads();
  float mean2 = 0.f, var2 = 0.f;
#pragma unroll
  for (int i = 0; i < 8; ++i) { mean2 += red[i]; var2 += red2[i]; }
  mean2 *= (1.f / 128.f);
  var2 = var2 * (1.f / 128.f) - mean2 * mean2;
  if (h == 0) yl[d] = (o - mean2) * rsqrtf(var2 + LN_EPS_) * lnsg[d] + lnsb[d];
  __syncthreads();
  float q = quadSum(quarterDot(Wq + (size_t)d * 128, yl, h));
  if (h == 0) xl[d] = q;      // reuse xl as q-vector
  __syncthreads();
  float qv = waveReduceSum(h == 0 ? q * f_b2[d] : 0.f);
  if (lane == 0) red[w] = qv;
  float qf = quadSum(quarterDot(FW2T + (size_t)d * 128, xl, h));
  __syncthreads();
  if (t == 0) {
    float qb = 0.f;
#pragma unroll
    for (int i = 0; i < 8; ++i) qb += red[i];
    ws[OFF_QB + bs] = qb * SCALE;
  }
  if (h == 0) {
    float offd = -(sp0 * ws[OFF_GFD + d * 2 + 0] + sp1 * ws[OFF_GFD + d * 2 + 1]);
    ws[OFF_OQ + (bs * 128 + d) * 2 + 0] = offd;
    ws[OFF_OQ + (bs * 128 + d) * 2 + 1] = qf * SCALE;
  }
}

// ---------------- write outputs ----------------
__global__ __launch_bounds__(256) void kOut(const float* __restrict__ ws,
                                            const float* __restrict__ S_r,
                                            const float* __restrict__ S_s,
                                            float* __restrict__ out) {
  int i = blockIdx.x * 256 + threadIdx.x;
  if (i < 8192) out[i] = ws[OFF_SLOTS + i];
  else if (i < 8320) out[i] = ws[OFF_SP + i - 8192];
  else if (i < 8576) out[i] = S_r[i - 8320];
  else if (i < 8704) out[i] = S_s[i - 8576];
}

extern "C" void kernel_launch(void* const* d_in, const int* in_sizes, int n_in,
                              void* d_out, int out_size, void* d_ws, size_t ws_size,
                              hipStream_t stream) {
  const float* inputs     = (const float*)d_in[0];
  const float* slots_init = (const float*)d_in[1];
  const float* S_p0       = (const float*)d_in[2];
  const float* S_s        = (const float*)d_in[3];
  const float* S_r        = (const float*)d_in[4];
  const float* Wq   = (const float*)d_in[5];
  const float* Wk   = (const float*)d_in[6];
  const float* Wv   = (const float*)d_in[7];
  const float* g_w  = (const float*)d_in[8];
  const float* g_b  = (const float*)d_in[9];
  const float* f_w1 = (const float*)d_in[10];
  const float* f_b1 = (const float*)d_in[11];
  const float* f_w2 = (const float*)d_in[12];
  const float* f_b2 = (const float*)d_in[13];
  const float* gwih = (const float*)d_in[14];
  const float* gwhh = (const float*)d_in[15];
  const float* gbih = (const float*)d_in[16];
  const float* gbhh = (const float*)d_in[17];
  const float* mw1  = (const float*)d_in[18];
  const float* mb1  = (const float*)d_in[19];
  const float* mw2  = (const float*)d_in[20];
  const float* mb2  = (const float*)d_in[21];
  const float* lnsg = (const float*)d_in[22];
  const float* lnsb = (const float*)d_in[23];
  const float* lnpg = (const float*)d_in[24];
  const float* lnpb = (const float*)d_in[25];
  float* ws  = (float*)d_ws;
  float* out = (float*)d_out;

  hipMemcpyAsync(ws + OFF_SLOTS, slots_init, 8192 * sizeof(float),
                 hipMemcpyDeviceToDevice, stream);
  hipMemcpyAsync(ws + OFF_SP, S_p0, 128 * sizeof(float),
                 hipMemcpyDeviceToDevice, stream);
  kCast<<<2048, 256, 0, stream>>>(inputs, ws);
  kFold<<<131, 256, 0, stream>>>(f_w1, Wk, Wv, g_w, g_b, f_b1, f_w2, ws);
  kBase<<<dim3(256, 2), 256, 0, stream>>>(ws);
  kQ<<<64, 256, 0, stream>>>(Wq, f_w2, f_b2, lnsg, lnsb, ws);
  for (int it = 0; it < 3; ++it) {
    kAttn<<<512, 256, 0, stream>>>(ws);
    kCQ<<<64, 512, 0, stream>>>(Wq, f_w2, f_b2, gwih, gwhh, gbih, gbhh,
                                mw1, mb1, mw2, mb2, lnpg, lnpb, lnsg, lnsb, ws);
  }
  kOut<<<34, 256, 0, stream>>>(ws, S_r, S_s, out);
}